// Round 1
// baseline (2064.402 us; speedup 1.0000x reference)
//
#include <hip/hip_runtime.h>
#include <math.h>

#define NB 16      // batch
#define CIN 3
#define LL 2048
#define DD 256
#define KK 8
#define NDEPTH 4
#define FF 1025
#define LOGL 11

__device__ inline float2 cmul(const float2 a, const float2 b){
    return make_float2(a.x*b.x - a.y*b.y, a.x*b.y + a.y*b.x);
}

// ---------------- twiddle table: tw[j] = exp(-2*pi*i*j/2048), j=0..1023 -------------
__global__ void twiddle_kernel(float2* __restrict__ tw){
    int j = blockIdx.x*blockDim.x + threadIdx.x;
    if (j < LL/2){
        double ang = -2.0*3.14159265358979323846*(double)j/(double)LL;
        tw[j] = make_float2((float)cos(ang), (float)sin(ang));
    }
}

// ---------------- transpose GLU weights: [layer][o][d] -> [layer][d][o] -------------
__global__ void transpose_glu_kernel(const float* __restrict__ wv, const float* __restrict__ wg,
                                     float* __restrict__ wvt, float* __restrict__ wgt){
    int idx = blockIdx.x*blockDim.x + threadIdx.x; // over NDEPTH*DD*DD
    int layer = idx >> 16;
    int rem   = idx & 65535;
    int d = rem >> 8, o = rem & 255;
    wvt[(layer<<16) + (d<<8) + o] = wv[(layer<<16) + (o<<8) + d];
    wgt[(layer<<16) + (d<<8) + o] = wg[(layer<<16) + (o<<8) + d];
}

// ---------------- lift: h[b,d,t] = lift_w[d,:3].x[b,:,t] + lift_w[d,3]*coord + b ----
__global__ void lift_kernel(const float* __restrict__ x, const float* __restrict__ lw,
                            const float* __restrict__ lb, float* __restrict__ h){
    int idx = blockIdx.x*blockDim.x + threadIdx.x; // NB*DD*LL
    int t = idx & (LL-1);
    int d = (idx >> LOGL) & (DD-1);
    int b = idx >> (LOGL+8);
    float coord = (float)t * (1.0f/(LL-1));
    const float* xb = x + (size_t)b*CIN*LL;
    float v = lb[d];
    v = fmaf(lw[d*4+0], xb[t],        v);
    v = fmaf(lw[d*4+1], xb[LL+t],     v);
    v = fmaf(lw[d*4+2], xb[2*LL+t],   v);
    v = fmaf(lw[d*4+3], coord,        v);
    h[idx] = v;
}

// ---------------- LayerNorm over channel dim d for each (b,t) -----------------------
__global__ void ln_kernel(const float* __restrict__ h, const float* __restrict__ gamma,
                          const float* __restrict__ beta, float* __restrict__ z){
    int gid = blockIdx.x*blockDim.x + threadIdx.x; // NB*LL
    int t = gid & (LL-1);
    int b = gid >> LOGL;
    const float* hp = h + (size_t)b*DD*LL + t;
    float s = 0.f;
    #pragma unroll 8
    for (int d = 0; d < DD; ++d) s += hp[(size_t)d*LL];
    float mu = s * (1.0f/DD);
    float ss = 0.f;
    #pragma unroll 8
    for (int d = 0; d < DD; ++d){ float v = hp[(size_t)d*LL]-mu; ss = fmaf(v, v, ss); }
    float inv = rsqrtf(ss*(1.0f/DD) + 1e-5f);
    float* zp = z + (size_t)b*DD*LL + t;
    #pragma unroll 4
    for (int d = 0; d < DD; ++d){
        zp[(size_t)d*LL] = (hp[(size_t)d*LL]-mu)*inv*gamma[d] + beta[d];
    }
}

// ---------------- forward FFT (real input, keep f=0..1024) --------------------------
__global__ __launch_bounds__(256) void fft_fwd_kernel(const float* __restrict__ in,
                                                      float2* __restrict__ out,
                                                      const float2* __restrict__ tw){
    __shared__ float2 a[LL];
    int sig = blockIdx.x;
    const float* src = in + (size_t)sig*LL;
    int tid = threadIdx.x;
    #pragma unroll
    for (int i = 0; i < LL/256; ++i){
        int idx = tid + i*256;
        int rev = __brev((unsigned)idx) >> (32-LOGL);
        a[rev] = make_float2(src[idx], 0.f);
    }
    __syncthreads();
    for (int s = 0; s < LOGL; ++s){
        int half = 1 << s;
        #pragma unroll
        for (int jj = 0; jj < 4; ++jj){
            int j = tid + jj*256;
            int grp = j >> s;
            int pos = j & (half-1);
            int i1 = (grp << (s+1)) + pos;
            int i2 = i1 + half;
            float2 w = tw[pos << (LOGL-1-s)];
            float2 u = a[i1];
            float2 v = cmul(w, a[i2]);
            a[i1] = make_float2(u.x+v.x, u.y+v.y);
            a[i2] = make_float2(u.x-v.x, u.y-v.y);
        }
        __syncthreads();
    }
    float2* dst = out + (size_t)sig*FF;
    #pragma unroll
    for (int i = 0; i < 5; ++i){
        int f = tid + i*256;
        if (f < FF) dst[f] = a[f];
    }
}

// ---------------- inverse FFT (Hermitian input f=0..1024, real output) --------------
__global__ __launch_bounds__(256) void fft_inv_kernel(const float2* __restrict__ in,
                                                      float* __restrict__ out,
                                                      const float2* __restrict__ tw){
    __shared__ float2 a[LL];
    int sig = blockIdx.x;
    const float2* src = in + (size_t)sig*FF;
    int tid = threadIdx.x;
    #pragma unroll
    for (int i = 0; i < LL/256; ++i){
        int idx = tid + i*256;
        float2 v;
        if (idx <= LL/2){ v = src[idx]; }
        else { v = src[LL-idx]; v.y = -v.y; }
        int rev = __brev((unsigned)idx) >> (32-LOGL);
        a[rev] = v;
    }
    __syncthreads();
    for (int s = 0; s < LOGL; ++s){
        int half = 1 << s;
        #pragma unroll
        for (int jj = 0; jj < 4; ++jj){
            int j = tid + jj*256;
            int grp = j >> s;
            int pos = j & (half-1);
            int i1 = (grp << (s+1)) + pos;
            int i2 = i1 + half;
            float2 w = tw[pos << (LOGL-1-s)];
            w.y = -w.y;   // conj twiddle for inverse
            float2 u = a[i1];
            float2 v = cmul(w, a[i2]);
            a[i1] = make_float2(u.x+v.x, u.y+v.y);
            a[i2] = make_float2(u.x-v.x, u.y-v.y);
        }
        __syncthreads();
    }
    float* dst = out + (size_t)sig*LL;
    const float scale = 1.0f/(float)LL;
    #pragma unroll
    for (int i = 0; i < LL/256; ++i){
        int idx = tid + i*256;
        dst[idx] = a[idx].x * scale;
    }
}

// ---------------- spectral mix: Sf[b,h,f] = sum_d Xf[b,d,f] * W[h,d,f] --------------
// W[h,d,f] = sum_l theta[l,h,d] * conj(phi[l,f]), built on the fly per (d,f).
__global__ __launch_bounds__(256) void spectral_kernel(const float2* __restrict__ Xf,
                                                       const float* __restrict__ theta, // [KK][DD][DD]
                                                       const float* __restrict__ phr,
                                                       const float* __restrict__ phim,
                                                       float2* __restrict__ Sf){
    __shared__ float  th[KK][16][16];   // [l][h_local][dd]   8 KB
    __shared__ float2 xf[16][16][16];   // [dd][b][f_local]  32 KB
    int tid = threadIdx.x;
    int fl = tid & 15, hl = tid >> 4;
    int f0 = blockIdx.x * 16;
    int h  = blockIdx.y * 16 + hl;
    int f  = f0 + fl;
    bool fok = (f < FF);

    float pr[KK], pi[KK];
    #pragma unroll
    for (int l = 0; l < KK; ++l){
        pr[l] = fok ? phr[l*FF + f]   : 0.f;
        pi[l] = fok ? -phim[l*FF + f] : 0.f;   // conj(phi)
    }

    float2 acc[NB];
    #pragma unroll
    for (int b = 0; b < NB; ++b) acc[b] = make_float2(0.f, 0.f);

    for (int dc = 0; dc < DD/16; ++dc){
        __syncthreads();
        // stage theta[l, h_tile, d_chunk]: 2048 floats
        #pragma unroll
        for (int i = 0; i < 8; ++i){
            int e = tid + i*256;
            int l = e >> 8; int rem = e & 255;
            int hh = rem >> 4, dd2 = rem & 15;
            th[l][hh][dd2] = theta[ ((size_t)(l*DD) + (blockIdx.y*16 + hh))*DD + dc*16 + dd2 ];
        }
        // stage Xf[b, d_chunk, f_tile]: 4096 float2
        #pragma unroll
        for (int i = 0; i < 16; ++i){
            int e = tid + i*256;
            int dd2 = e >> 8; int rem = e & 255;
            int b = rem >> 4, ff2 = rem & 15;
            int fg = f0 + ff2;
            float2 v = make_float2(0.f, 0.f);
            if (fg < FF) v = Xf[ ((size_t)(b*DD) + dc*16 + dd2)*FF + fg ];
            xf[dd2][b][ff2] = v;
        }
        __syncthreads();

        for (int dd2 = 0; dd2 < 16; ++dd2){
            float wre = 0.f, wim = 0.f;
            #pragma unroll
            for (int l = 0; l < KK; ++l){
                float t = th[l][hl][dd2];
                wre = fmaf(t, pr[l], wre);
                wim = fmaf(t, pi[l], wim);
            }
            #pragma unroll
            for (int b = 0; b < NB; ++b){
                float2 x = xf[dd2][b][fl];
                acc[b].x = fmaf(x.x, wre, fmaf(-x.y, wim, acc[b].x));
                acc[b].y = fmaf(x.x, wim, fmaf( x.y, wre, acc[b].y));
            }
        }
    }
    if (fok){
        #pragma unroll
        for (int b = 0; b < NB; ++b){
            Sf[ ((size_t)(b*DD) + h)*FF + f ] = acc[b];
        }
    }
}

// ---------------- GLU: h[b,o,t] += (Wv S + bv) * sigmoid(Wg S + bg) -----------------
__global__ __launch_bounds__(256) void glu_kernel(const float* __restrict__ S,
                                                  const float* __restrict__ wvt,  // [d][o]
                                                  const float* __restrict__ wgt,  // [d][o]
                                                  const float* __restrict__ bv,
                                                  const float* __restrict__ bg,
                                                  float* __restrict__ h){
    __shared__ float st[DD][32];   // 32 KB
    int tid = threadIdx.x;         // o
    int b = blockIdx.y;
    int t0 = blockIdx.x * 32;
    const float* Sp = S + (size_t)b*DD*LL + t0;
    #pragma unroll
    for (int i = 0; i < 32; ++i){
        int e = tid + i*256;
        int d = e >> 5, t = e & 31;
        st[d][t] = Sp[(size_t)d*LL + t];
    }
    __syncthreads();
    float accv[32], accg[32];
    #pragma unroll
    for (int t = 0; t < 32; ++t){ accv[t] = 0.f; accg[t] = 0.f; }
    for (int d = 0; d < DD; ++d){
        float wv = wvt[d*DD + tid];
        float wg = wgt[d*DD + tid];
        #pragma unroll
        for (int t4 = 0; t4 < 8; ++t4){
            float4 s4 = *reinterpret_cast<const float4*>(&st[d][t4*4]);
            accv[t4*4+0] = fmaf(wv, s4.x, accv[t4*4+0]);
            accv[t4*4+1] = fmaf(wv, s4.y, accv[t4*4+1]);
            accv[t4*4+2] = fmaf(wv, s4.z, accv[t4*4+2]);
            accv[t4*4+3] = fmaf(wv, s4.w, accv[t4*4+3]);
            accg[t4*4+0] = fmaf(wg, s4.x, accg[t4*4+0]);
            accg[t4*4+1] = fmaf(wg, s4.y, accg[t4*4+1]);
            accg[t4*4+2] = fmaf(wg, s4.z, accg[t4*4+2]);
            accg[t4*4+3] = fmaf(wg, s4.w, accg[t4*4+3]);
        }
    }
    float bvv = bv[tid], bgv = bg[tid];
    float* hp = h + ((size_t)b*DD + tid)*LL + t0;
    #pragma unroll
    for (int t = 0; t < 32; ++t){
        float v = accv[t] + bvv;
        float g = accg[t] + bgv;
        g = 1.0f/(1.0f + __expf(-g));
        hp[t] += v*g;
    }
}

// ---------------- head: y[b,t] = head_w . h[b,:,t] + head_b -------------------------
__global__ void head_kernel(const float* __restrict__ h, const float* __restrict__ hw,
                            const float* __restrict__ hb, float* __restrict__ out){
    int gid = blockIdx.x*blockDim.x + threadIdx.x; // NB*LL
    int t = gid & (LL-1);
    int b = gid >> LOGL;
    const float* hp = h + (size_t)b*DD*LL + t;
    float s = hb[0];
    #pragma unroll 8
    for (int d = 0; d < DD; ++d) s = fmaf(hw[d], hp[(size_t)d*LL], s);
    out[gid] = s;
}

extern "C" void kernel_launch(void* const* d_in, const int* in_sizes, int n_in,
                              void* d_out, int out_size, void* d_ws, size_t ws_size,
                              hipStream_t stream){
    (void)in_sizes; (void)n_in; (void)out_size; (void)ws_size;
    const float* x      = (const float*)d_in[0];
    const float* lift_w = (const float*)d_in[1];
    const float* lift_b = (const float*)d_in[2];
    const float* theta  = (const float*)d_in[3];
    const float* ln_g   = (const float*)d_in[4];
    const float* ln_b   = (const float*)d_in[5];
    const float* gvw    = (const float*)d_in[6];
    const float* gvb    = (const float*)d_in[7];
    const float* ggw    = (const float*)d_in[8];
    const float* ggb    = (const float*)d_in[9];
    const float* hw     = (const float*)d_in[10];
    const float* hb     = (const float*)d_in[11];
    const float* phr    = (const float*)d_in[12];
    const float* phim   = (const float*)d_in[13];
    float* out = (float*)d_out;

    char* ws = (char*)d_ws;
    size_t off = 0;
    float2* tw  = (float2*)(ws + off); off += (size_t)(LL/2)*sizeof(float2);
    float*  wvt = (float*)(ws + off);  off += (size_t)NDEPTH*DD*DD*4;
    float*  wgt = (float*)(ws + off);  off += (size_t)NDEPTH*DD*DD*4;
    off = (off + 255) & ~(size_t)255;
    float*  h   = (float*)(ws + off);  off += (size_t)NB*DD*LL*4;
    float*  z   = (float*)(ws + off);  off += (size_t)NB*DD*LL*4;   // aliased with S
    float*  S   = z;   // safe: z fully consumed by fft_fwd before fft_inv writes S
    float2* Xf  = (float2*)(ws + off); off += (size_t)NB*DD*FF*8;
    float2* Sf  = (float2*)(ws + off); off += (size_t)NB*DD*FF*8;

    twiddle_kernel<<<4, 256, 0, stream>>>(tw);
    transpose_glu_kernel<<<(NDEPTH*DD*DD)/256, 256, 0, stream>>>(gvw, ggw, wvt, wgt);
    lift_kernel<<<(NB*DD*LL)/256, 256, 0, stream>>>(x, lift_w, lift_b, h);

    for (int layer = 0; layer < NDEPTH; ++layer){
        ln_kernel<<<(NB*LL)/256, 256, 0, stream>>>(h, ln_g + layer*DD, ln_b + layer*DD, z);
        fft_fwd_kernel<<<NB*DD, 256, 0, stream>>>(z, Xf, tw);
        dim3 sg((FF+15)/16, DD/16);
        spectral_kernel<<<sg, 256, 0, stream>>>(Xf, theta + (size_t)layer*KK*DD*DD, phr, phim, Sf);
        fft_inv_kernel<<<NB*DD, 256, 0, stream>>>(Sf, S, tw);
        dim3 gg(LL/32, NB);
        glu_kernel<<<gg, 256, 0, stream>>>(S, wvt + (size_t)layer*DD*DD, wgt + (size_t)layer*DD*DD,
                                           gvb + layer*DD, ggb + layer*DD, h);
    }
    head_kernel<<<(NB*LL)/256, 256, 0, stream>>>(h, hw, hb, out);
}

// Round 2
// 1752.171 us; speedup vs baseline: 1.1782x; 1.1782x over previous
//
#include <hip/hip_runtime.h>
#include <math.h>

#define NB 16      // batch
#define CIN 3
#define LL 2048
#define DD 256
#define KK 8
#define NDEPTH 4
#define FF 1025
#define LOGL 11

__device__ inline float2 cmul(const float2 a, const float2 b){
    return make_float2(a.x*b.x - a.y*b.y, a.x*b.y + a.y*b.x);
}

// ---------------- twiddle table: tw[j] = exp(-2*pi*i*j/2048), j=0..1023 -------------
__global__ void twiddle_kernel(float2* __restrict__ tw){
    int j = blockIdx.x*blockDim.x + threadIdx.x;
    if (j < LL/2){
        double ang = -2.0*3.14159265358979323846*(double)j/(double)LL;
        tw[j] = make_float2((float)cos(ang), (float)sin(ang));
    }
}

// ---------------- transpose GLU weights: [layer][o][d] -> [layer][d][o] -------------
__global__ void transpose_glu_kernel(const float* __restrict__ wv, const float* __restrict__ wg,
                                     float* __restrict__ wvt, float* __restrict__ wgt){
    int idx = blockIdx.x*blockDim.x + threadIdx.x; // over NDEPTH*DD*DD
    int layer = idx >> 16;
    int rem   = idx & 65535;
    int d = rem >> 8, o = rem & 255;
    wvt[(layer<<16) + (d<<8) + o] = wv[(layer<<16) + (o<<8) + d];
    wgt[(layer<<16) + (d<<8) + o] = wg[(layer<<16) + (o<<8) + d];
}

// ---------------- transpose theta: [m][h][d] -> [m][d][h], m = layer*KK+l ----------
__global__ void transpose_theta_kernel(const float* __restrict__ in, float* __restrict__ out){
    __shared__ float tile[32][33];
    int m = blockIdx.z;
    int c0 = blockIdx.x*32, r0 = blockIdx.y*32;
    int tx = threadIdx.x & 31, ty = threadIdx.x >> 5;  // 32 x 8
    const float* src = in + (size_t)m*DD*DD;
    float* dst = out + (size_t)m*DD*DD;
    #pragma unroll
    for (int i = 0; i < 4; ++i){
        tile[ty + i*8][tx] = src[(size_t)(r0 + ty + i*8)*DD + c0 + tx];
    }
    __syncthreads();
    #pragma unroll
    for (int i = 0; i < 4; ++i){
        dst[(size_t)(c0 + ty + i*8)*DD + r0 + tx] = tile[tx][ty + i*8];
    }
}

// ---------------- lift ------------------------------------------------------------
__global__ void lift_kernel(const float* __restrict__ x, const float* __restrict__ lw,
                            const float* __restrict__ lb, float* __restrict__ h){
    int idx = blockIdx.x*blockDim.x + threadIdx.x; // NB*DD*LL
    int t = idx & (LL-1);
    int d = (idx >> LOGL) & (DD-1);
    int b = idx >> (LOGL+8);
    float coord = (float)t * (1.0f/(LL-1));
    const float* xb = x + (size_t)b*CIN*LL;
    float v = lb[d];
    v = fmaf(lw[d*4+0], xb[t],        v);
    v = fmaf(lw[d*4+1], xb[LL+t],     v);
    v = fmaf(lw[d*4+2], xb[2*LL+t],   v);
    v = fmaf(lw[d*4+3], coord,        v);
    h[idx] = v;
}

// ---------------- LayerNorm over channel dim d for each (b,t) -----------------------
__global__ void ln_kernel(const float* __restrict__ h, const float* __restrict__ gamma,
                          const float* __restrict__ beta, float* __restrict__ z){
    int gid = blockIdx.x*blockDim.x + threadIdx.x; // NB*LL
    int t = gid & (LL-1);
    int b = gid >> LOGL;
    const float* hp = h + (size_t)b*DD*LL + t;
    float s = 0.f;
    #pragma unroll 8
    for (int d = 0; d < DD; ++d) s += hp[(size_t)d*LL];
    float mu = s * (1.0f/DD);
    float ss = 0.f;
    #pragma unroll 8
    for (int d = 0; d < DD; ++d){ float v = hp[(size_t)d*LL]-mu; ss = fmaf(v, v, ss); }
    float inv = rsqrtf(ss*(1.0f/DD) + 1e-5f);
    float* zp = z + (size_t)b*DD*LL + t;
    #pragma unroll 4
    for (int d = 0; d < DD; ++d){
        zp[(size_t)d*LL] = (hp[(size_t)d*LL]-mu)*inv*gamma[d] + beta[d];
    }
}

// ---------------- forward FFT (real input, keep f=0..1024) --------------------------
__global__ __launch_bounds__(256) void fft_fwd_kernel(const float* __restrict__ in,
                                                      float2* __restrict__ out,
                                                      const float2* __restrict__ tw){
    __shared__ float2 a[LL];
    int sig = blockIdx.x;
    const float* src = in + (size_t)sig*LL;
    int tid = threadIdx.x;
    #pragma unroll
    for (int i = 0; i < LL/256; ++i){
        int idx = tid + i*256;
        int rev = __brev((unsigned)idx) >> (32-LOGL);
        a[rev] = make_float2(src[idx], 0.f);
    }
    __syncthreads();
    for (int s = 0; s < LOGL; ++s){
        int half = 1 << s;
        #pragma unroll
        for (int jj = 0; jj < 4; ++jj){
            int j = tid + jj*256;
            int grp = j >> s;
            int pos = j & (half-1);
            int i1 = (grp << (s+1)) + pos;
            int i2 = i1 + half;
            float2 w = tw[pos << (LOGL-1-s)];
            float2 u = a[i1];
            float2 v = cmul(w, a[i2]);
            a[i1] = make_float2(u.x+v.x, u.y+v.y);
            a[i2] = make_float2(u.x-v.x, u.y-v.y);
        }
        __syncthreads();
    }
    float2* dst = out + (size_t)sig*FF;
    #pragma unroll
    for (int i = 0; i < 5; ++i){
        int f = tid + i*256;
        if (f < FF) dst[f] = a[f];
    }
}

// ---------------- inverse FFT (Hermitian input f=0..1024, real output) --------------
__global__ __launch_bounds__(256) void fft_inv_kernel(const float2* __restrict__ in,
                                                      float* __restrict__ out,
                                                      const float2* __restrict__ tw){
    __shared__ float2 a[LL];
    int sig = blockIdx.x;
    const float2* src = in + (size_t)sig*FF;
    int tid = threadIdx.x;
    #pragma unroll
    for (int i = 0; i < LL/256; ++i){
        int idx = tid + i*256;
        float2 v;
        if (idx <= LL/2){ v = src[idx]; }
        else { v = src[LL-idx]; v.y = -v.y; }
        int rev = __brev((unsigned)idx) >> (32-LOGL);
        a[rev] = v;
    }
    __syncthreads();
    for (int s = 0; s < LOGL; ++s){
        int half = 1 << s;
        #pragma unroll
        for (int jj = 0; jj < 4; ++jj){
            int j = tid + jj*256;
            int grp = j >> s;
            int pos = j & (half-1);
            int i1 = (grp << (s+1)) + pos;
            int i2 = i1 + half;
            float2 w = tw[pos << (LOGL-1-s)];
            w.y = -w.y;   // conj twiddle for inverse
            float2 u = a[i1];
            float2 v = cmul(w, a[i2]);
            a[i1] = make_float2(u.x+v.x, u.y+v.y);
            a[i2] = make_float2(u.x-v.x, u.y-v.y);
        }
        __syncthreads();
    }
    float* dst = out + (size_t)sig*LL;
    const float scale = 1.0f/(float)LL;
    #pragma unroll
    for (int i = 0; i < LL/256; ++i){
        int idx = tid + i*256;
        dst[idx] = a[idx].x * scale;
    }
}

// ---------------- spectral v2: Sf[b,h,f] = sum_d Xf[b,d,f]*W[h,d,f], f<1024 ---------
// W[h,d,f] = sum_l thetaT[l,d,h]*conj(phi[l,f]). Block: 64 h x 16 f x 8 b.
// Per thread: 4 h x 8 b complex accumulators.
__global__ __launch_bounds__(256) void spectral2_kernel(const float2* __restrict__ Xf,
    const float* __restrict__ thetaT,  // [KK][DD d][DD h] for this layer
    const float* __restrict__ phr, const float* __restrict__ phim,
    float2* __restrict__ Sf){
    __shared__ __align__(16) float th[8][KK][64];     // [dd][l][h]  16 KB
    __shared__ __align__(16) float2 xf[8][8][16];     // [dd][bb][fl] 8 KB
    int tid = threadIdx.x;
    int fl = tid & 15, hl = tid >> 4;   // hl 0..15
    int hl4 = hl*4;
    int f0 = blockIdx.x * 16;           // 0..1008 (f<1024 always; Nyquist separate)
    int h0 = blockIdx.y * 64;
    int b0 = blockIdx.z * 8;
    int f = f0 + fl;

    float pr[KK], pi[KK];
    #pragma unroll
    for (int l = 0; l < KK; ++l){ pr[l] = phr[l*FF + f]; pi[l] = -phim[l*FF + f]; }

    float2 acc[4][8];
    #pragma unroll
    for (int i = 0; i < 4; ++i)
        #pragma unroll
        for (int bb = 0; bb < 8; ++bb) acc[i][bb] = make_float2(0.f, 0.f);

    for (int dc = 0; dc < DD/8; ++dc){
        // stage theta chunk: 8 dd x 8 l x 64 h = 4096 floats (coalesced, h fastest)
        #pragma unroll
        for (int i = 0; i < 16; ++i){
            int e = tid + i*256;
            int hh = e & 63, l = (e >> 6) & 7, dd2 = e >> 9;
            ((float*)th)[e] = thetaT[((size_t)l*DD + dc*8 + dd2)*DD + h0 + hh];
        }
        // stage Xf chunk: 8 dd x 8 bb x 16 fl float2 (coalesced, f fastest)
        #pragma unroll
        for (int i = 0; i < 4; ++i){
            int e = tid + i*256;
            int ffl = e & 15, bb = (e >> 4) & 7, dd2 = e >> 7;
            ((float2*)xf)[e] = Xf[((size_t)(b0+bb)*DD + dc*8 + dd2)*FF + f0 + ffl];
        }
        __syncthreads();
        #pragma unroll 2
        for (int dd = 0; dd < 8; ++dd){
            float wre[4] = {0.f,0.f,0.f,0.f}, wim[4] = {0.f,0.f,0.f,0.f};
            #pragma unroll
            for (int l = 0; l < KK; ++l){
                float4 t = *(const float4*)&th[dd][l][hl4];
                float prl = pr[l], pil = pi[l];
                wre[0] = fmaf(t.x, prl, wre[0]); wre[1] = fmaf(t.y, prl, wre[1]);
                wre[2] = fmaf(t.z, prl, wre[2]); wre[3] = fmaf(t.w, prl, wre[3]);
                wim[0] = fmaf(t.x, pil, wim[0]); wim[1] = fmaf(t.y, pil, wim[1]);
                wim[2] = fmaf(t.z, pil, wim[2]); wim[3] = fmaf(t.w, pil, wim[3]);
            }
            #pragma unroll
            for (int bb = 0; bb < 8; ++bb){
                float2 x = xf[dd][bb][fl];
                #pragma unroll
                for (int i = 0; i < 4; ++i){
                    acc[i][bb].x = fmaf(x.x, wre[i], fmaf(-x.y, wim[i], acc[i][bb].x));
                    acc[i][bb].y = fmaf(x.x, wim[i], fmaf( x.y, wre[i], acc[i][bb].y));
                }
            }
        }
        __syncthreads();
    }
    #pragma unroll
    for (int bb = 0; bb < 8; ++bb){
        #pragma unroll
        for (int i = 0; i < 4; ++i){
            Sf[((size_t)(b0+bb)*DD + h0 + hl4 + i)*FF + f] = acc[i][bb];
        }
    }
}

// ---------------- Nyquist bin f=1024: Sf[b,h,1024] ---------------------------------
__global__ __launch_bounds__(256) void nyq_kernel(const float2* __restrict__ Xf,
    const float* __restrict__ thetaT,
    const float* __restrict__ phr, const float* __restrict__ phim,
    float2* __restrict__ Sf){
    __shared__ float2 red[256];
    int tid = threadIdx.x;
    int hb = blockIdx.x, b = blockIdx.y;
    int h = hb*16 + (tid & 15);
    int dp = tid >> 4;
    float pr[KK], pi[KK];
    #pragma unroll
    for (int l = 0; l < KK; ++l){ pr[l] = phr[l*FF + 1024]; pi[l] = -phim[l*FF + 1024]; }
    float2 acc = make_float2(0.f, 0.f);
    for (int j = 0; j < 16; ++j){
        int d = dp*16 + j;
        float wre = 0.f, wim = 0.f;
        #pragma unroll
        for (int l = 0; l < KK; ++l){
            float t = thetaT[((size_t)l*DD + d)*DD + h];
            wre = fmaf(t, pr[l], wre);
            wim = fmaf(t, pi[l], wim);
        }
        float2 x = Xf[((size_t)b*DD + d)*FF + 1024];
        acc.x = fmaf(x.x, wre, fmaf(-x.y, wim, acc.x));
        acc.y = fmaf(x.x, wim, fmaf( x.y, wre, acc.y));
    }
    red[tid] = acc;
    __syncthreads();
    if (tid < 16){
        float2 s = make_float2(0.f, 0.f);
        #pragma unroll
        for (int k = 0; k < 16; ++k){ s.x += red[tid + k*16].x; s.y += red[tid + k*16].y; }
        Sf[((size_t)b*DD + hb*16 + tid)*FF + 1024] = s;
    }
}

// ---------------- GLU v2: h[b,o,t] += (Wv S + bv)*sigmoid(Wg S + bg), t-tile 64 -----
__global__ __launch_bounds__(256) void glu2_kernel(const float* __restrict__ S,
    const float* __restrict__ wvt,  // [d][o]
    const float* __restrict__ wgt,  // [d][o]
    const float* __restrict__ bv, const float* __restrict__ bg,
    float* __restrict__ h){
    __shared__ __align__(16) float st[DD*64];   // 64 KB
    int tid = threadIdx.x;                      // o
    int b = blockIdx.y;
    int t0 = blockIdx.x * 64;
    const float* Sp = S + (size_t)b*DD*LL + t0;
    #pragma unroll 8
    for (int i = 0; i < 64; ++i){
        int e = tid + i*256;
        st[e] = Sp[(size_t)(e >> 6)*LL + (e & 63)];
    }
    __syncthreads();
    float4 av[16], ag[16];
    #pragma unroll
    for (int t4 = 0; t4 < 16; ++t4){
        av[t4] = make_float4(0.f,0.f,0.f,0.f);
        ag[t4] = make_float4(0.f,0.f,0.f,0.f);
    }
    for (int d = 0; d < DD; ++d){
        float wv = wvt[d*DD + tid];
        float wg = wgt[d*DD + tid];
        const float* row = &st[d*64];
        #pragma unroll
        for (int t4 = 0; t4 < 16; ++t4){
            float4 s = *(const float4*)&row[t4*4];
            av[t4].x = fmaf(wv, s.x, av[t4].x); av[t4].y = fmaf(wv, s.y, av[t4].y);
            av[t4].z = fmaf(wv, s.z, av[t4].z); av[t4].w = fmaf(wv, s.w, av[t4].w);
            ag[t4].x = fmaf(wg, s.x, ag[t4].x); ag[t4].y = fmaf(wg, s.y, ag[t4].y);
            ag[t4].z = fmaf(wg, s.z, ag[t4].z); ag[t4].w = fmaf(wg, s.w, ag[t4].w);
        }
    }
    float bvv = bv[tid], bgv = bg[tid];
    __syncthreads();
    #pragma unroll
    for (int t4 = 0; t4 < 16; ++t4){
        float4 v = av[t4], g = ag[t4];
        v.x += bvv; v.y += bvv; v.z += bvv; v.w += bvv;
        g.x += bgv; g.y += bgv; g.z += bgv; g.w += bgv;
        g.x = 1.f/(1.f+__expf(-g.x)); g.y = 1.f/(1.f+__expf(-g.y));
        g.z = 1.f/(1.f+__expf(-g.z)); g.w = 1.f/(1.f+__expf(-g.w));
        float4 r = make_float4(v.x*g.x, v.y*g.y, v.z*g.z, v.w*g.w);
        *(float4*)&st[tid*64 + t4*4] = r;
    }
    __syncthreads();
    float* hp = h + (size_t)b*DD*LL + t0;
    #pragma unroll
    for (int i = 0; i < 16; ++i){
        int e = tid + i*256;            // float4 index
        int d = e >> 4, t4 = e & 15;
        float4 r = *(const float4*)&st[d*64 + t4*4];
        float* dst = hp + (size_t)d*LL + t4*4;
        float4 cur = *(const float4*)dst;
        cur.x += r.x; cur.y += r.y; cur.z += r.z; cur.w += r.w;
        *(float4*)dst = cur;
    }
}

// ---------------- head ------------------------------------------------------------
__global__ void head_kernel(const float* __restrict__ h, const float* __restrict__ hw,
                            const float* __restrict__ hb, float* __restrict__ out){
    int gid = blockIdx.x*blockDim.x + threadIdx.x; // NB*LL
    int t = gid & (LL-1);
    int b = gid >> LOGL;
    const float* hp = h + (size_t)b*DD*LL + t;
    float s = hb[0];
    #pragma unroll 8
    for (int d = 0; d < DD; ++d) s = fmaf(hw[d], hp[(size_t)d*LL], s);
    out[gid] = s;
}

extern "C" void kernel_launch(void* const* d_in, const int* in_sizes, int n_in,
                              void* d_out, int out_size, void* d_ws, size_t ws_size,
                              hipStream_t stream){
    (void)in_sizes; (void)n_in; (void)out_size; (void)ws_size;
    const float* x      = (const float*)d_in[0];
    const float* lift_w = (const float*)d_in[1];
    const float* lift_b = (const float*)d_in[2];
    const float* theta  = (const float*)d_in[3];
    const float* ln_g   = (const float*)d_in[4];
    const float* ln_b   = (const float*)d_in[5];
    const float* gvw    = (const float*)d_in[6];
    const float* gvb    = (const float*)d_in[7];
    const float* ggw    = (const float*)d_in[8];
    const float* ggb    = (const float*)d_in[9];
    const float* hw     = (const float*)d_in[10];
    const float* hb     = (const float*)d_in[11];
    const float* phr    = (const float*)d_in[12];
    const float* phim   = (const float*)d_in[13];
    float* out = (float*)d_out;

    char* ws = (char*)d_ws;
    size_t off = 0;
    float2* tw  = (float2*)(ws + off); off += (size_t)(LL/2)*sizeof(float2);
    float*  wvt = (float*)(ws + off);  off += (size_t)NDEPTH*DD*DD*4;
    float*  wgt = (float*)(ws + off);  off += (size_t)NDEPTH*DD*DD*4;
    float*  thT = (float*)(ws + off);  off += (size_t)NDEPTH*KK*DD*DD*4;
    off = (off + 255) & ~(size_t)255;
    float*  h   = (float*)(ws + off);  off += (size_t)NB*DD*LL*4;
    float*  z   = (float*)(ws + off);  off += (size_t)NB*DD*LL*4;   // aliased with S
    float*  S   = z;   // safe: z fully consumed by fft_fwd before fft_inv writes S
    float2* Xf  = (float2*)(ws + off); off += (size_t)NB*DD*FF*8;
    float2* Sf  = (float2*)(ws + off); off += (size_t)NB*DD*FF*8;

    twiddle_kernel<<<4, 256, 0, stream>>>(tw);
    transpose_glu_kernel<<<(NDEPTH*DD*DD)/256, 256, 0, stream>>>(gvw, ggw, wvt, wgt);
    transpose_theta_kernel<<<dim3(8,8,NDEPTH*KK), 256, 0, stream>>>(theta, thT);
    lift_kernel<<<(NB*DD*LL)/256, 256, 0, stream>>>(x, lift_w, lift_b, h);

    for (int layer = 0; layer < NDEPTH; ++layer){
        const float* thL = thT + (size_t)layer*KK*DD*DD;
        ln_kernel<<<(NB*LL)/256, 256, 0, stream>>>(h, ln_g + layer*DD, ln_b + layer*DD, z);
        fft_fwd_kernel<<<NB*DD, 256, 0, stream>>>(z, Xf, tw);
        spectral2_kernel<<<dim3(64,4,2), 256, 0, stream>>>(Xf, thL, phr, phim, Sf);
        nyq_kernel<<<dim3(16,16), 256, 0, stream>>>(Xf, thL, phr, phim, Sf);
        fft_inv_kernel<<<NB*DD, 256, 0, stream>>>(Sf, S, tw);
        glu2_kernel<<<dim3(LL/64, NB), 256, 0, stream>>>(S, wvt + (size_t)layer*DD*DD, wgt + (size_t)layer*DD*DD,
                                                         gvb + layer*DD, ggb + layer*DD, h);
    }
    head_kernel<<<(NB*LL)/256, 256, 0, stream>>>(h, hw, hb, out);
}

// Round 3
// 1457.028 us; speedup vs baseline: 1.4169x; 1.2026x over previous
//
#include <hip/hip_runtime.h>
#include <math.h>

#define NB 16      // batch
#define CIN 3
#define LL 2048
#define DD 256
#define KK 8
#define NDEPTH 4
#define FF 1025
#define LOGL 11

__device__ inline float2 cmul(const float2 a, const float2 b){
    return make_float2(a.x*b.x - a.y*b.y, a.x*b.y + a.y*b.x);
}

// ---------------- twiddle table: tw[j] = exp(-2*pi*i*j/2048), j=0..1023 -------------
__global__ void twiddle_kernel(float2* __restrict__ tw){
    int j = blockIdx.x*blockDim.x + threadIdx.x;
    if (j < LL/2){
        double ang = -2.0*3.14159265358979323846*(double)j/(double)LL;
        tw[j] = make_float2((float)cos(ang), (float)sin(ang));
    }
}

// ---------------- transpose GLU weights: [layer][o][d] -> [layer][d][o] -------------
__global__ void transpose_glu_kernel(const float* __restrict__ wv, const float* __restrict__ wg,
                                     float* __restrict__ wvt, float* __restrict__ wgt){
    int idx = blockIdx.x*blockDim.x + threadIdx.x; // over NDEPTH*DD*DD
    int layer = idx >> 16;
    int rem   = idx & 65535;
    int d = rem >> 8, o = rem & 255;
    wvt[(layer<<16) + (d<<8) + o] = wv[(layer<<16) + (o<<8) + d];
    wgt[(layer<<16) + (d<<8) + o] = wg[(layer<<16) + (o<<8) + d];
}

// ---------------- transpose theta: [m][h][d] -> [m][d][h], m = layer*KK+l ----------
__global__ void transpose_theta_kernel(const float* __restrict__ in, float* __restrict__ out){
    __shared__ float tile[32][33];
    int m = blockIdx.z;
    int c0 = blockIdx.x*32, r0 = blockIdx.y*32;
    int tx = threadIdx.x & 31, ty = threadIdx.x >> 5;  // 32 x 8
    const float* src = in + (size_t)m*DD*DD;
    float* dst = out + (size_t)m*DD*DD;
    #pragma unroll
    for (int i = 0; i < 4; ++i){
        tile[ty + i*8][tx] = src[(size_t)(r0 + ty + i*8)*DD + c0 + tx];
    }
    __syncthreads();
    #pragma unroll
    for (int i = 0; i < 4; ++i){
        dst[(size_t)(c0 + ty + i*8)*DD + r0 + tx] = tile[tx][ty + i*8];
    }
}

// ---------------- lift + LayerNorm(layer 0): writes h and z -------------------------
// block: 256 threads = 64 t x 4 dgroup; each thread computes 64 d-values for one t.
__global__ __launch_bounds__(256) void lift_ln_kernel(const float* __restrict__ x,
        const float* __restrict__ lw, const float* __restrict__ lb,
        const float* __restrict__ gamma, const float* __restrict__ beta,
        float* __restrict__ h, float* __restrict__ z){
    __shared__ float red[2][4][64];
    __shared__ float stat[2][64];
    __shared__ float gb[512];
    int tid = threadIdx.x;
    int t = tid & 63, dg = tid >> 6;
    int b = blockIdx.y;
    int tg = blockIdx.x*64 + t;
    gb[tid] = gamma[tid];
    gb[256 + tid] = beta[tid];
    const float* xb = x + (size_t)b*CIN*LL;
    float x0 = xb[tg], x1 = xb[LL + tg], x2 = xb[2*LL + tg];
    float coord = (float)tg * (1.0f/(LL-1));
    float hv[64];
    float s = 0.f, ss = 0.f;
    float* hp = h + (size_t)b*DD*LL + tg;
    #pragma unroll
    for (int j = 0; j < 64; ++j){
        int d = dg*64 + j;
        float4 w = *(const float4*)&lw[d*4];
        float v = lb[d];
        v = fmaf(w.x, x0, v); v = fmaf(w.y, x1, v);
        v = fmaf(w.z, x2, v); v = fmaf(w.w, coord, v);
        hv[j] = v;
        s += v; ss = fmaf(v, v, ss);
        hp[(size_t)d*LL] = v;
    }
    red[0][dg][t] = s; red[1][dg][t] = ss;
    __syncthreads();
    if (tid < 64){
        float S1 = red[0][0][tid] + red[0][1][tid] + red[0][2][tid] + red[0][3][tid];
        float S2 = red[1][0][tid] + red[1][1][tid] + red[1][2][tid] + red[1][3][tid];
        float mu = S1*(1.0f/DD);
        float var = S2*(1.0f/DD) - mu*mu;
        stat[0][tid] = mu;
        stat[1][tid] = rsqrtf(var + 1e-5f);
    }
    __syncthreads();
    float mu = stat[0][t], rs = stat[1][t];
    float* zp = z + (size_t)b*DD*LL + tg;
    #pragma unroll
    for (int j = 0; j < 64; ++j){
        int d = dg*64 + j;
        zp[(size_t)d*LL] = (hv[j] - mu)*rs*gb[d] + gb[256 + d];
    }
}

// ---------------- forward FFT, 2 real channels packed as complex --------------------
__global__ __launch_bounds__(256) void fft_fwd_pair_kernel(const float* __restrict__ in,
                                                           float2* __restrict__ out,
                                                           const float2* __restrict__ tw){
    __shared__ float2 a[LL];
    int blk = blockIdx.x;                    // (b*128 + dpair)
    const float* src0 = in + (size_t)(blk*2)*LL;
    const float* src1 = src0 + LL;
    int tid = threadIdx.x;
    #pragma unroll
    for (int i = 0; i < LL/256; ++i){
        int idx = tid + i*256;
        int rev = __brev((unsigned)idx) >> (32-LOGL);
        a[rev] = make_float2(src0[idx], src1[idx]);
    }
    __syncthreads();
    for (int s = 0; s < LOGL; ++s){
        int half = 1 << s;
        #pragma unroll
        for (int jj = 0; jj < 4; ++jj){
            int j = tid + jj*256;
            int grp = j >> s;
            int pos = j & (half-1);
            int i1 = (grp << (s+1)) + pos;
            int i2 = i1 + half;
            float2 w = tw[pos << (LOGL-1-s)];
            float2 u = a[i1];
            float2 v = cmul(w, a[i2]);
            a[i1] = make_float2(u.x+v.x, u.y+v.y);
            a[i2] = make_float2(u.x-v.x, u.y-v.y);
        }
        __syncthreads();
    }
    float2* dst0 = out + (size_t)(blk*2)*FF;
    float2* dst1 = dst0 + FF;
    #pragma unroll
    for (int i = 0; i < 5; ++i){
        int f = tid + i*256;
        if (f <= 1024){
            int m = (LL - f) & (LL-1);
            float2 A = a[f], B = a[m];
            dst0[f] = make_float2(0.5f*(A.x + B.x), 0.5f*(A.y - B.y));
            dst1[f] = make_float2(0.5f*(A.y + B.y), 0.5f*(B.x - A.x));
        }
    }
}

// ---------------- inverse FFT, 2 Hermitian spectra packed as complex ----------------
__global__ __launch_bounds__(256) void fft_inv_pair_kernel(const float2* __restrict__ in,
                                                           float* __restrict__ out,
                                                           const float2* __restrict__ tw){
    __shared__ float2 a[LL];
    int blk = blockIdx.x;                    // (b*128 + hpair)
    const float2* src0 = in + (size_t)(blk*2)*FF;
    const float2* src1 = src0 + FF;
    int tid = threadIdx.x;
    #pragma unroll
    for (int i = 0; i < LL/256; ++i){
        int idx = tid + i*256;
        float2 Y;
        if (idx <= 1024){
            float2 s0 = src0[idx], s1 = src1[idx];
            Y = make_float2(s0.x - s1.y, s0.y + s1.x);
        } else {
            int m = LL - idx;
            float2 s0 = src0[m], s1 = src1[m];
            Y = make_float2(s0.x + s1.y, s1.x - s0.y);
        }
        int rev = __brev((unsigned)idx) >> (32-LOGL);
        a[rev] = Y;
    }
    __syncthreads();
    for (int s = 0; s < LOGL; ++s){
        int half = 1 << s;
        #pragma unroll
        for (int jj = 0; jj < 4; ++jj){
            int j = tid + jj*256;
            int grp = j >> s;
            int pos = j & (half-1);
            int i1 = (grp << (s+1)) + pos;
            int i2 = i1 + half;
            float2 w = tw[pos << (LOGL-1-s)];
            w.y = -w.y;   // conj twiddle for inverse
            float2 u = a[i1];
            float2 v = cmul(w, a[i2]);
            a[i1] = make_float2(u.x+v.x, u.y+v.y);
            a[i2] = make_float2(u.x-v.x, u.y-v.y);
        }
        __syncthreads();
    }
    float* dst0 = out + (size_t)(blk*2)*LL;
    float* dst1 = dst0 + LL;
    const float sc = 1.0f/(float)LL;
    #pragma unroll
    for (int i = 0; i < LL/256; ++i){
        int idx = tid + i*256;
        float2 v = a[idx];
        dst0[idx] = v.x*sc;
        dst1[idx] = v.y*sc;
    }
}

// ---------------- spectral v2: Sf[b,h,f] = sum_d Xf[b,d,f]*W[h,d,f], f<1024 ---------
__global__ __launch_bounds__(256) void spectral2_kernel(const float2* __restrict__ Xf,
    const float* __restrict__ thetaT,  // [KK][DD d][DD h] for this layer
    const float* __restrict__ phr, const float* __restrict__ phim,
    float2* __restrict__ Sf){
    __shared__ __align__(16) float th[8][KK][64];     // [dd][l][h]  16 KB
    __shared__ __align__(16) float2 xf[8][8][16];     // [dd][bb][fl] 8 KB
    int tid = threadIdx.x;
    int fl = tid & 15, hl = tid >> 4;   // hl 0..15
    int hl4 = hl*4;
    int f0 = blockIdx.x * 16;           // f<1024 always; Nyquist separate
    int h0 = blockIdx.y * 64;
    int b0 = blockIdx.z * 8;
    int f = f0 + fl;

    float pr[KK], pi[KK];
    #pragma unroll
    for (int l = 0; l < KK; ++l){ pr[l] = phr[l*FF + f]; pi[l] = -phim[l*FF + f]; }

    float2 acc[4][8];
    #pragma unroll
    for (int i = 0; i < 4; ++i)
        #pragma unroll
        for (int bb = 0; bb < 8; ++bb) acc[i][bb] = make_float2(0.f, 0.f);

    for (int dc = 0; dc < DD/8; ++dc){
        #pragma unroll
        for (int i = 0; i < 16; ++i){
            int e = tid + i*256;
            int hh = e & 63, l = (e >> 6) & 7, dd2 = e >> 9;
            ((float*)th)[e] = thetaT[((size_t)l*DD + dc*8 + dd2)*DD + h0 + hh];
        }
        #pragma unroll
        for (int i = 0; i < 4; ++i){
            int e = tid + i*256;
            int ffl = e & 15, bb = (e >> 4) & 7, dd2 = e >> 7;
            ((float2*)xf)[e] = Xf[((size_t)(b0+bb)*DD + dc*8 + dd2)*FF + f0 + ffl];
        }
        __syncthreads();
        #pragma unroll 2
        for (int dd = 0; dd < 8; ++dd){
            float wre[4] = {0.f,0.f,0.f,0.f}, wim[4] = {0.f,0.f,0.f,0.f};
            #pragma unroll
            for (int l = 0; l < KK; ++l){
                float4 t = *(const float4*)&th[dd][l][hl4];
                float prl = pr[l], pil = pi[l];
                wre[0] = fmaf(t.x, prl, wre[0]); wre[1] = fmaf(t.y, prl, wre[1]);
                wre[2] = fmaf(t.z, prl, wre[2]); wre[3] = fmaf(t.w, prl, wre[3]);
                wim[0] = fmaf(t.x, pil, wim[0]); wim[1] = fmaf(t.y, pil, wim[1]);
                wim[2] = fmaf(t.z, pil, wim[2]); wim[3] = fmaf(t.w, pil, wim[3]);
            }
            #pragma unroll
            for (int bb = 0; bb < 8; ++bb){
                float2 x = xf[dd][bb][fl];
                #pragma unroll
                for (int i = 0; i < 4; ++i){
                    acc[i][bb].x = fmaf(x.x, wre[i], fmaf(-x.y, wim[i], acc[i][bb].x));
                    acc[i][bb].y = fmaf(x.x, wim[i], fmaf( x.y, wre[i], acc[i][bb].y));
                }
            }
        }
        __syncthreads();
    }
    #pragma unroll
    for (int bb = 0; bb < 8; ++bb){
        #pragma unroll
        for (int i = 0; i < 4; ++i){
            Sf[((size_t)(b0+bb)*DD + h0 + hl4 + i)*FF + f] = acc[i][bb];
        }
    }
}

// ---------------- Nyquist bin f=1024 ------------------------------------------------
__global__ __launch_bounds__(256) void nyq_kernel(const float2* __restrict__ Xf,
    const float* __restrict__ thetaT,
    const float* __restrict__ phr, const float* __restrict__ phim,
    float2* __restrict__ Sf){
    __shared__ float2 red[256];
    int tid = threadIdx.x;
    int hb = blockIdx.x, b = blockIdx.y;
    int h = hb*16 + (tid & 15);
    int dp = tid >> 4;
    float pr[KK], pi[KK];
    #pragma unroll
    for (int l = 0; l < KK; ++l){ pr[l] = phr[l*FF + 1024]; pi[l] = -phim[l*FF + 1024]; }
    float2 acc = make_float2(0.f, 0.f);
    for (int j = 0; j < 16; ++j){
        int d = dp*16 + j;
        float wre = 0.f, wim = 0.f;
        #pragma unroll
        for (int l = 0; l < KK; ++l){
            float t = thetaT[((size_t)l*DD + d)*DD + h];
            wre = fmaf(t, pr[l], wre);
            wim = fmaf(t, pi[l], wim);
        }
        float2 x = Xf[((size_t)b*DD + d)*FF + 1024];
        acc.x = fmaf(x.x, wre, fmaf(-x.y, wim, acc.x));
        acc.y = fmaf(x.x, wim, fmaf( x.y, wre, acc.y));
    }
    red[tid] = acc;
    __syncthreads();
    if (tid < 16){
        float2 s = make_float2(0.f, 0.f);
        #pragma unroll
        for (int k = 0; k < 16; ++k){ s.x += red[tid + k*16].x; s.y += red[tid + k*16].y; }
        Sf[((size_t)b*DD + hb*16 + tid)*FF + 1024] = s;
    }
}

// ---------------- GLU + residual + fused epilogue -----------------------------------
// MODE 0: write h (+=GLU), write z = LayerNorm(h) [aux1=gamma, aux2=beta, outp=z]
// MODE 1: last layer: don't write h; write y = head(h)  [aux1=head_w, aux2=head_b, outp=y]
template<int MODE>
__global__ __launch_bounds__(256) void glu_ln_kernel(const float* __restrict__ S,
    const float* __restrict__ wvt,  // [d][o]
    const float* __restrict__ wgt,  // [d][o]
    const float* __restrict__ bv, const float* __restrict__ bg,
    float* __restrict__ h, float* __restrict__ outp,
    const float* __restrict__ aux1, const float* __restrict__ aux2){
    __shared__ __align__(16) float st[DD*64];   // 64 KB
    __shared__ float red[2][4][64];
    __shared__ float stat[2][64];
    __shared__ float gb[512];
    int tid = threadIdx.x;                      // o
    int b = blockIdx.y;
    int t0 = blockIdx.x * 64;
    const float* Sp = S + (size_t)b*DD*LL + t0;
    #pragma unroll 8
    for (int i = 0; i < 64; ++i){
        int e = tid + i*256;
        st[e] = Sp[(size_t)(e >> 6)*LL + (e & 63)];
    }
    gb[tid] = aux1[tid];
    if (MODE == 0) gb[256 + tid] = aux2[tid];
    __syncthreads();
    float4 av[16], ag[16];
    #pragma unroll
    for (int t4 = 0; t4 < 16; ++t4){
        av[t4] = make_float4(0.f,0.f,0.f,0.f);
        ag[t4] = make_float4(0.f,0.f,0.f,0.f);
    }
    for (int d = 0; d < DD; ++d){
        float wv = wvt[d*DD + tid];
        float wg = wgt[d*DD + tid];
        const float* row = &st[d*64];
        #pragma unroll
        for (int t4 = 0; t4 < 16; ++t4){
            float4 s = *(const float4*)&row[t4*4];
            av[t4].x = fmaf(wv, s.x, av[t4].x); av[t4].y = fmaf(wv, s.y, av[t4].y);
            av[t4].z = fmaf(wv, s.z, av[t4].z); av[t4].w = fmaf(wv, s.w, av[t4].w);
            ag[t4].x = fmaf(wg, s.x, ag[t4].x); ag[t4].y = fmaf(wg, s.y, ag[t4].y);
            ag[t4].z = fmaf(wg, s.z, ag[t4].z); ag[t4].w = fmaf(wg, s.w, ag[t4].w);
        }
    }
    float bvv = bv[tid], bgv = bg[tid];
    __syncthreads();
    #pragma unroll
    for (int t4 = 0; t4 < 16; ++t4){
        float4 v = av[t4], g = ag[t4];
        v.x += bvv; v.y += bvv; v.z += bvv; v.w += bvv;
        g.x += bgv; g.y += bgv; g.z += bgv; g.w += bgv;
        g.x = 1.f/(1.f+__expf(-g.x)); g.y = 1.f/(1.f+__expf(-g.y));
        g.z = 1.f/(1.f+__expf(-g.z)); g.w = 1.f/(1.f+__expf(-g.w));
        float4 r = make_float4(v.x*g.x, v.y*g.y, v.z*g.z, v.w*g.w);
        *(float4*)&st[tid*64 + t4*4] = r;
    }
    __syncthreads();
    // redistribute: cur = h_old + r; (MODE0: write h); store cur back to st
    float* hp = h + (size_t)b*DD*LL + t0;
    #pragma unroll
    for (int i = 0; i < 16; ++i){
        int e = tid + i*256;            // float4 index
        int d = e >> 4, t4 = e & 15;
        float4 r = *(const float4*)&st[d*64 + t4*4];
        float* hdst = hp + (size_t)d*LL + t4*4;
        float4 cur = *(const float4*)hdst;
        cur.x += r.x; cur.y += r.y; cur.z += r.z; cur.w += r.w;
        if (MODE == 0) *(float4*)hdst = cur;
        *(float4*)&st[d*64 + t4*4] = cur;
    }
    __syncthreads();
    // per-t reduction over d (lanes along t: 2-way bank aliasing = free)
    int t = tid & 63, dg = tid >> 6;
    float s = 0.f, ss = 0.f;
    #pragma unroll
    for (int j = 0; j < 64; ++j){
        float v = st[(dg*64 + j)*64 + t];
        if (MODE == 0){ s += v; ss = fmaf(v, v, ss); }
        else { s = fmaf(gb[dg*64 + j], v, s); }
    }
    red[0][dg][t] = s;
    if (MODE == 0) red[1][dg][t] = ss;
    __syncthreads();
    if (MODE == 0){
        if (tid < 64){
            float S1 = red[0][0][tid] + red[0][1][tid] + red[0][2][tid] + red[0][3][tid];
            float S2 = red[1][0][tid] + red[1][1][tid] + red[1][2][tid] + red[1][3][tid];
            float mu = S1*(1.0f/DD);
            float var = S2*(1.0f/DD) - mu*mu;
            stat[0][tid] = mu;
            stat[1][tid] = rsqrtf(var + 1e-5f);
        }
        __syncthreads();
        float* zp = outp + (size_t)b*DD*LL + t0;
        #pragma unroll
        for (int i = 0; i < 16; ++i){
            int e = tid + i*256;
            int d = e >> 4, t4 = e & 15;
            float4 cur = *(const float4*)&st[d*64 + t4*4];
            float g = gb[d], be = gb[256 + d];
            float4 zv;
            zv.x = (cur.x - stat[0][t4*4+0])*stat[1][t4*4+0]*g + be;
            zv.y = (cur.y - stat[0][t4*4+1])*stat[1][t4*4+1]*g + be;
            zv.z = (cur.z - stat[0][t4*4+2])*stat[1][t4*4+2]*g + be;
            zv.w = (cur.w - stat[0][t4*4+3])*stat[1][t4*4+3]*g + be;
            *(float4*)(zp + (size_t)d*LL + t4*4) = zv;
        }
    } else {
        if (tid < 64){
            float S1 = red[0][0][tid] + red[0][1][tid] + red[0][2][tid] + red[0][3][tid];
            outp[(size_t)b*LL + t0 + tid] = S1 + aux2[0];
        }
    }
}

extern "C" void kernel_launch(void* const* d_in, const int* in_sizes, int n_in,
                              void* d_out, int out_size, void* d_ws, size_t ws_size,
                              hipStream_t stream){
    (void)in_sizes; (void)n_in; (void)out_size; (void)ws_size;
    const float* x      = (const float*)d_in[0];
    const float* lift_w = (const float*)d_in[1];
    const float* lift_b = (const float*)d_in[2];
    const float* theta  = (const float*)d_in[3];
    const float* ln_g   = (const float*)d_in[4];
    const float* ln_b   = (const float*)d_in[5];
    const float* gvw    = (const float*)d_in[6];
    const float* gvb    = (const float*)d_in[7];
    const float* ggw    = (const float*)d_in[8];
    const float* ggb    = (const float*)d_in[9];
    const float* hw     = (const float*)d_in[10];
    const float* hb     = (const float*)d_in[11];
    const float* phr    = (const float*)d_in[12];
    const float* phim   = (const float*)d_in[13];
    float* out = (float*)d_out;

    char* ws = (char*)d_ws;
    size_t off = 0;
    float2* tw  = (float2*)(ws + off); off += (size_t)(LL/2)*sizeof(float2);
    float*  wvt = (float*)(ws + off);  off += (size_t)NDEPTH*DD*DD*4;
    float*  wgt = (float*)(ws + off);  off += (size_t)NDEPTH*DD*DD*4;
    float*  thT = (float*)(ws + off);  off += (size_t)NDEPTH*KK*DD*DD*4;
    off = (off + 255) & ~(size_t)255;
    float*  h   = (float*)(ws + off);  off += (size_t)NB*DD*LL*4;
    float*  z   = (float*)(ws + off);  off += (size_t)NB*DD*LL*4;   // aliased with S
    float*  S   = z;   // safe: per-block tile read fully before same-tile write
    float2* Xf  = (float2*)(ws + off); off += (size_t)NB*DD*FF*8;
    float2* Sf  = (float2*)(ws + off); off += (size_t)NB*DD*FF*8;

    twiddle_kernel<<<4, 256, 0, stream>>>(tw);
    transpose_glu_kernel<<<(NDEPTH*DD*DD)/256, 256, 0, stream>>>(gvw, ggw, wvt, wgt);
    transpose_theta_kernel<<<dim3(8,8,NDEPTH*KK), 256, 0, stream>>>(theta, thT);
    lift_ln_kernel<<<dim3(LL/64, NB), 256, 0, stream>>>(x, lift_w, lift_b, ln_g, ln_b, h, z);

    for (int layer = 0; layer < NDEPTH; ++layer){
        const float* thL = thT + (size_t)layer*KK*DD*DD;
        fft_fwd_pair_kernel<<<NB*DD/2, 256, 0, stream>>>(z, Xf, tw);
        spectral2_kernel<<<dim3(64,4,2), 256, 0, stream>>>(Xf, thL, phr, phim, Sf);
        nyq_kernel<<<dim3(16,16), 256, 0, stream>>>(Xf, thL, phr, phim, Sf);
        fft_inv_pair_kernel<<<NB*DD/2, 256, 0, stream>>>(Sf, S, tw);
        if (layer < NDEPTH-1){
            glu_ln_kernel<0><<<dim3(LL/64, NB), 256, 0, stream>>>(
                S, wvt + (size_t)layer*DD*DD, wgt + (size_t)layer*DD*DD,
                gvb + layer*DD, ggb + layer*DD, h, z,
                ln_g + (layer+1)*DD, ln_b + (layer+1)*DD);
        } else {
            glu_ln_kernel<1><<<dim3(LL/64, NB), 256, 0, stream>>>(
                S, wvt + (size_t)layer*DD*DD, wgt + (size_t)layer*DD*DD,
                gvb + layer*DD, ggb + layer*DD, h, out, hw, hb);
        }
    }
}

// Round 4
// 1018.637 us; speedup vs baseline: 2.0266x; 1.4304x over previous
//
#include <hip/hip_runtime.h>
#include <math.h>

#define NB 16      // batch
#define CIN 3
#define LL 2048
#define DD 256
#define KK 8
#define NDEPTH 4
#define FF 1025
#define FFP 1032   // padded F stride for half2 Xf (FFP*4 % 32 == 0)
#define LOGL 11

typedef _Float16 half8 __attribute__((ext_vector_type(8)));
typedef float f32x4 __attribute__((ext_vector_type(4)));

union H8 { half8 h8; unsigned int u[4]; };
union H2 { _Float16 h[2]; unsigned int u; };

__device__ inline float2 cmul(const float2 a, const float2 b){
    return make_float2(a.x*b.x - a.y*b.y, a.x*b.y + a.y*b.x);
}

// ---------------- twiddle table ----------------------------------------------------
__global__ void twiddle_kernel(float2* __restrict__ tw){
    int j = blockIdx.x*blockDim.x + threadIdx.x;
    if (j < LL/2){
        double ang = -2.0*3.14159265358979323846*(double)j/(double)LL;
        tw[j] = make_float2((float)cos(ang), (float)sin(ang));
    }
}

// ---------------- transpose GLU weights: [layer][o][d] -> [layer][d][o] -------------
__global__ void transpose_glu_kernel(const float* __restrict__ wv, const float* __restrict__ wg,
                                     float* __restrict__ wvt, float* __restrict__ wgt){
    int idx = blockIdx.x*blockDim.x + threadIdx.x;
    int layer = idx >> 16;
    int rem   = idx & 65535;
    int d = rem >> 8, o = rem & 255;
    wvt[(layer<<16) + (d<<8) + o] = wv[(layer<<16) + (o<<8) + d];
    wgt[(layer<<16) + (d<<8) + o] = wg[(layer<<16) + (o<<8) + d];
}

// ---------------- transpose theta: [m][h][d] -> [m][d][h], m = layer*KK+l ----------
__global__ void transpose_theta_kernel(const float* __restrict__ in, float* __restrict__ out){
    __shared__ float tile[32][33];
    int m = blockIdx.z;
    int c0 = blockIdx.x*32, r0 = blockIdx.y*32;
    int tx = threadIdx.x & 31, ty = threadIdx.x >> 5;
    const float* src = in + (size_t)m*DD*DD;
    float* dst = out + (size_t)m*DD*DD;
    #pragma unroll
    for (int i = 0; i < 4; ++i){
        tile[ty + i*8][tx] = src[(size_t)(r0 + ty + i*8)*DD + c0 + tx];
    }
    __syncthreads();
    #pragma unroll
    for (int i = 0; i < 4; ++i){
        dst[(size_t)(c0 + ty + i*8)*DD + r0 + tx] = tile[tx][ty + i*8];
    }
}

// ---------------- lift + LayerNorm(layer 0) ----------------------------------------
__global__ __launch_bounds__(256) void lift_ln_kernel(const float* __restrict__ x,
        const float* __restrict__ lw, const float* __restrict__ lb,
        const float* __restrict__ gamma, const float* __restrict__ beta,
        float* __restrict__ h, float* __restrict__ z){
    __shared__ float red[2][4][64];
    __shared__ float stat[2][64];
    __shared__ float gb[512];
    int tid = threadIdx.x;
    int t = tid & 63, dg = tid >> 6;
    int b = blockIdx.y;
    int tg = blockIdx.x*64 + t;
    gb[tid] = gamma[tid];
    gb[256 + tid] = beta[tid];
    const float* xb = x + (size_t)b*CIN*LL;
    float x0 = xb[tg], x1 = xb[LL + tg], x2 = xb[2*LL + tg];
    float coord = (float)tg * (1.0f/(LL-1));
    float hv[64];
    float s = 0.f, ss = 0.f;
    float* hp = h + (size_t)b*DD*LL + tg;
    #pragma unroll
    for (int j = 0; j < 64; ++j){
        int d = dg*64 + j;
        float4 w = *(const float4*)&lw[d*4];
        float v = lb[d];
        v = fmaf(w.x, x0, v); v = fmaf(w.y, x1, v);
        v = fmaf(w.z, x2, v); v = fmaf(w.w, coord, v);
        hv[j] = v;
        s += v; ss = fmaf(v, v, ss);
        hp[(size_t)d*LL] = v;
    }
    red[0][dg][t] = s; red[1][dg][t] = ss;
    __syncthreads();
    if (tid < 64){
        float S1 = red[0][0][tid] + red[0][1][tid] + red[0][2][tid] + red[0][3][tid];
        float S2 = red[1][0][tid] + red[1][1][tid] + red[1][2][tid] + red[1][3][tid];
        float mu = S1*(1.0f/DD);
        float var = S2*(1.0f/DD) - mu*mu;
        stat[0][tid] = mu;
        stat[1][tid] = rsqrtf(var + 1e-5f);
    }
    __syncthreads();
    float mu = stat[0][t], rs = stat[1][t];
    float* zp = z + (size_t)b*DD*LL + tg;
    #pragma unroll
    for (int j = 0; j < 64; ++j){
        int d = dg*64 + j;
        zp[(size_t)d*LL] = (hv[j] - mu)*rs*gb[d] + gb[256 + d];
    }
}

// ---------------- forward FFT, 2 real channels packed; outputs half2 (re,im) -------
__global__ __launch_bounds__(256) void fft_fwd_pair_kernel(const float* __restrict__ in,
                                                           unsigned int* __restrict__ XfH,
                                                           const float2* __restrict__ tw){
    __shared__ float2 a[LL];
    int blk = blockIdx.x;
    const float* src0 = in + (size_t)(blk*2)*LL;
    const float* src1 = src0 + LL;
    int tid = threadIdx.x;
    #pragma unroll
    for (int i = 0; i < LL/256; ++i){
        int idx = tid + i*256;
        int rev = __brev((unsigned)idx) >> (32-LOGL);
        a[rev] = make_float2(src0[idx], src1[idx]);
    }
    __syncthreads();
    for (int s = 0; s < LOGL; ++s){
        int half = 1 << s;
        #pragma unroll
        for (int jj = 0; jj < 4; ++jj){
            int j = tid + jj*256;
            int grp = j >> s;
            int pos = j & (half-1);
            int i1 = (grp << (s+1)) + pos;
            int i2 = i1 + half;
            float2 w = tw[pos << (LOGL-1-s)];
            float2 u = a[i1];
            float2 v = cmul(w, a[i2]);
            a[i1] = make_float2(u.x+v.x, u.y+v.y);
            a[i2] = make_float2(u.x-v.x, u.y-v.y);
        }
        __syncthreads();
    }
    unsigned int* dst0 = XfH + (size_t)(blk*2)*FFP;
    unsigned int* dst1 = dst0 + FFP;
    #pragma unroll
    for (int i = 0; i < 5; ++i){
        int f = tid + i*256;
        if (f <= 1024){
            int m = (LL - f) & (LL-1);
            float2 A = a[f], B = a[m];
            H2 p0, p1;
            p0.h[0] = (_Float16)(0.5f*(A.x + B.x));
            p0.h[1] = (_Float16)(0.5f*(A.y - B.y));
            p1.h[0] = (_Float16)(0.5f*(A.y + B.y));
            p1.h[1] = (_Float16)(0.5f*(B.x - A.x));
            dst0[f] = p0.u;
            dst1[f] = p1.u;
        }
    }
}

// ---------------- inverse FFT, 2 Hermitian spectra packed --------------------------
__global__ __launch_bounds__(256) void fft_inv_pair_kernel(const float2* __restrict__ in,
                                                           float* __restrict__ out,
                                                           const float2* __restrict__ tw){
    __shared__ float2 a[LL];
    int blk = blockIdx.x;
    const float2* src0 = in + (size_t)(blk*2)*FF;
    const float2* src1 = src0 + FF;
    int tid = threadIdx.x;
    #pragma unroll
    for (int i = 0; i < LL/256; ++i){
        int idx = tid + i*256;
        float2 Y;
        if (idx <= 1024){
            float2 s0 = src0[idx], s1 = src1[idx];
            Y = make_float2(s0.x - s1.y, s0.y + s1.x);
        } else {
            int m = LL - idx;
            float2 s0 = src0[m], s1 = src1[m];
            Y = make_float2(s0.x + s1.y, s1.x - s0.y);
        }
        int rev = __brev((unsigned)idx) >> (32-LOGL);
        a[rev] = Y;
    }
    __syncthreads();
    for (int s = 0; s < LOGL; ++s){
        int half = 1 << s;
        #pragma unroll
        for (int jj = 0; jj < 4; ++jj){
            int j = tid + jj*256;
            int grp = j >> s;
            int pos = j & (half-1);
            int i1 = (grp << (s+1)) + pos;
            int i2 = i1 + half;
            float2 w = tw[pos << (LOGL-1-s)];
            w.y = -w.y;
            float2 u = a[i1];
            float2 v = cmul(w, a[i2]);
            a[i1] = make_float2(u.x+v.x, u.y+v.y);
            a[i2] = make_float2(u.x-v.x, u.y-v.y);
        }
        __syncthreads();
    }
    float* dst0 = out + (size_t)(blk*2)*LL;
    float* dst1 = dst0 + LL;
    const float sc = 1.0f/(float)LL;
    #pragma unroll
    for (int i = 0; i < LL/256; ++i){
        int idx = tid + i*256;
        float2 v = a[idx];
        dst0[idx] = v.x*sc;
        dst1[idx] = v.y*sc;
    }
}

// ---------------- spectral v3: MFMA. f-tile=8, h-tile=64 (4 waves), all 16 b --------
// Sf[b,h,f] = sum_d Xf[b,d,f]*W[d,h,f]; W = sum_l thetaT[l,d,h]*conj(phi[l,f]).
// A (M=b16 x K=d32) from LDS fragments; B (K=d32 x N=h16) built in registers (f32->f16).
__global__ __launch_bounds__(256, 2) void spectral3_kernel(
    const unsigned int* __restrict__ XfH,   // [b][d][FFP] half2 (re,im)
    const float* __restrict__ thetaT,       // [KK][d][h] this layer
    const float* __restrict__ phr, const float* __restrict__ phim,
    float2* __restrict__ Sf){
    __shared__ unsigned int Apairs[8*64*8];   // 16 KB, swizzled fragment layout
    __shared__ float2 phi_s[8*KK];            // (pr, pi=-phim) per (ff,l)
    int tid = threadIdx.x;
    int w = tid >> 6, lane = tid & 63;
    int n = lane & 15, kp = lane >> 4;
    int f0 = blockIdx.x * 8;
    int h0 = blockIdx.y * 64;
    int h = h0 + w*16 + n;

    if (tid < 64){
        int ff = tid >> 3, l = tid & 7;
        phi_s[tid] = make_float2(phr[l*FF + f0 + ff], -phim[l*FF + f0 + ff]);
    }

    f32x4 accre[8], accim[8];
    #pragma unroll
    for (int i = 0; i < 8; ++i){
        accre[i] = (f32x4){0.f,0.f,0.f,0.f};
        accim[i] = (f32x4){0.f,0.f,0.f,0.f};
    }

    for (int kc = 0; kc < 8; ++kc){
        // theta for this k-chunk: th[l][j], d = kc*32 + kp*8 + j, fixed h
        float th[8][8];
        #pragma unroll
        for (int l = 0; l < 8; ++l)
            #pragma unroll
            for (int j = 0; j < 8; ++j)
                th[l][j] = thetaT[((size_t)(l*DD) + kc*32 + kp*8 + j)*DD + h];

        __syncthreads();   // previous iteration's A reads done
        // stage Xf fragments: slot = s*256+tid -> b = tid&15, dd = s*16 + (tid>>4)
        #pragma unroll
        for (int s = 0; s < 2; ++s){
            int b = tid & 15;
            int dd = s*16 + (tid >> 4);
            const uint4* src = (const uint4*)(XfH + ((size_t)(b*DD + kc*32 + dd)*FFP + f0));
            uint4 v0 = src[0], v1 = src[1];
            int L = b + 16*(dd >> 3), j = dd & 7;
            unsigned int vv[8] = {v0.x, v0.y, v0.z, v0.w, v1.x, v1.y, v1.z, v1.w};
            #pragma unroll
            for (int ff = 0; ff < 8; ++ff){
                int A = ff*2048 + L*32 + j*4;
                A ^= ((A >> 7) & 3) << 5;
                *(unsigned int*)((char*)Apairs + A) = vv[ff];
            }
        }
        __syncthreads();

        #pragma unroll
        for (int ff = 0; ff < 8; ++ff){
            // phi (wave-uniform broadcast reads)
            float pr[8], pi[8];
            #pragma unroll
            for (int l = 0; l < 8; ++l){
                float2 p = phi_s[ff*8 + l];
                pr[l] = p.x; pi[l] = p.y;
            }
            // A fragments
            int Ab = ff*2048 + lane*32;
            Ab ^= ((Ab >> 7) & 3) << 5;
            uint4 lo = *(const uint4*)((const char*)Apairs + Ab);
            uint4 hi = *(const uint4*)((const char*)Apairs + Ab + 16);
            unsigned int dw[8] = {lo.x, lo.y, lo.z, lo.w, hi.x, hi.y, hi.z, hi.w};
            H8 Are, Aim, Anim;
            #pragma unroll
            for (int k = 0; k < 4; ++k){
                Are.u[k]  = __builtin_amdgcn_perm(dw[2*k+1], dw[2*k], 0x05040100u);
                Aim.u[k]  = __builtin_amdgcn_perm(dw[2*k+1], dw[2*k], 0x07060302u);
                Anim.u[k] = Aim.u[k] ^ 0x80008000u;
            }
            // W build (f32) -> f16 B fragments
            float wre[8], wim[8];
            #pragma unroll
            for (int j = 0; j < 8; ++j){
                float re = 0.f, im = 0.f;
                #pragma unroll
                for (int l = 0; l < 8; ++l){
                    re = fmaf(th[l][j], pr[l], re);
                    im = fmaf(th[l][j], pi[l], im);
                }
                wre[j] = re; wim[j] = im;
            }
            H8 Bre, Bim;
            #pragma unroll
            for (int j = 0; j < 8; ++j){
                Bre.h8[j] = (_Float16)wre[j];
                Bim.h8[j] = (_Float16)wim[j];
            }
            // Sre = Xre*Wre - Xim*Wim ; Sim = Xre*Wim + Xim*Wre
            accre[ff] = __builtin_amdgcn_mfma_f32_16x16x32_f16(Are.h8,  Bre.h8, accre[ff], 0, 0, 0);
            accre[ff] = __builtin_amdgcn_mfma_f32_16x16x32_f16(Anim.h8, Bim.h8, accre[ff], 0, 0, 0);
            accim[ff] = __builtin_amdgcn_mfma_f32_16x16x32_f16(Are.h8,  Bim.h8, accim[ff], 0, 0, 0);
            accim[ff] = __builtin_amdgcn_mfma_f32_16x16x32_f16(Aim.h8,  Bre.h8, accim[ff], 0, 0, 0);
        }
    }
    // epilogue: D rows b = kp*4 + r, col = h
    #pragma unroll
    for (int ff = 0; ff < 8; ++ff){
        #pragma unroll
        for (int r = 0; r < 4; ++r){
            int b = kp*4 + r;
            Sf[((size_t)(b*DD) + h)*FF + f0 + ff] = make_float2(accre[ff][r], accim[ff][r]);
        }
    }
}

// ---------------- Nyquist bin f=1024 ------------------------------------------------
__global__ __launch_bounds__(256) void nyq_kernel(const unsigned int* __restrict__ XfH,
    const float* __restrict__ thetaT,
    const float* __restrict__ phr, const float* __restrict__ phim,
    float2* __restrict__ Sf){
    __shared__ float2 red[256];
    int tid = threadIdx.x;
    int hb = blockIdx.x, b = blockIdx.y;
    int h = hb*16 + (tid & 15);
    int dp = tid >> 4;
    float pr[KK], pi[KK];
    #pragma unroll
    for (int l = 0; l < KK; ++l){ pr[l] = phr[l*FF + 1024]; pi[l] = -phim[l*FF + 1024]; }
    float2 acc = make_float2(0.f, 0.f);
    for (int j = 0; j < 16; ++j){
        int d = dp*16 + j;
        float wre = 0.f, wim = 0.f;
        #pragma unroll
        for (int l = 0; l < KK; ++l){
            float t = thetaT[((size_t)l*DD + d)*DD + h];
            wre = fmaf(t, pr[l], wre);
            wim = fmaf(t, pi[l], wim);
        }
        H2 u; u.u = XfH[(size_t)(b*DD + d)*FFP + 1024];
        float2 x = make_float2((float)u.h[0], (float)u.h[1]);
        acc.x = fmaf(x.x, wre, fmaf(-x.y, wim, acc.x));
        acc.y = fmaf(x.x, wim, fmaf( x.y, wre, acc.y));
    }
    red[tid] = acc;
    __syncthreads();
    if (tid < 16){
        float2 s = make_float2(0.f, 0.f);
        #pragma unroll
        for (int k = 0; k < 16; ++k){ s.x += red[tid + k*16].x; s.y += red[tid + k*16].y; }
        Sf[((size_t)b*DD + hb*16 + tid)*FF + 1024] = s;
    }
}

// ---------------- GLU + residual + fused epilogue -----------------------------------
template<int MODE>
__global__ __launch_bounds__(256) void glu_ln_kernel(const float* __restrict__ S,
    const float* __restrict__ wvt, const float* __restrict__ wgt,
    const float* __restrict__ bv, const float* __restrict__ bg,
    float* __restrict__ h, float* __restrict__ outp,
    const float* __restrict__ aux1, const float* __restrict__ aux2){
    __shared__ __align__(16) float st[DD*64];
    __shared__ float red[2][4][64];
    __shared__ float stat[2][64];
    __shared__ float gb[512];
    int tid = threadIdx.x;
    int b = blockIdx.y;
    int t0 = blockIdx.x * 64;
    const float* Sp = S + (size_t)b*DD*LL + t0;
    #pragma unroll 8
    for (int i = 0; i < 64; ++i){
        int e = tid + i*256;
        st[e] = Sp[(size_t)(e >> 6)*LL + (e & 63)];
    }
    gb[tid] = aux1[tid];
    if (MODE == 0) gb[256 + tid] = aux2[tid];
    __syncthreads();
    float4 av[16], ag[16];
    #pragma unroll
    for (int t4 = 0; t4 < 16; ++t4){
        av[t4] = make_float4(0.f,0.f,0.f,0.f);
        ag[t4] = make_float4(0.f,0.f,0.f,0.f);
    }
    for (int d = 0; d < DD; ++d){
        float wv = wvt[d*DD + tid];
        float wg = wgt[d*DD + tid];
        const float* row = &st[d*64];
        #pragma unroll
        for (int t4 = 0; t4 < 16; ++t4){
            float4 s = *(const float4*)&row[t4*4];
            av[t4].x = fmaf(wv, s.x, av[t4].x); av[t4].y = fmaf(wv, s.y, av[t4].y);
            av[t4].z = fmaf(wv, s.z, av[t4].z); av[t4].w = fmaf(wv, s.w, av[t4].w);
            ag[t4].x = fmaf(wg, s.x, ag[t4].x); ag[t4].y = fmaf(wg, s.y, ag[t4].y);
            ag[t4].z = fmaf(wg, s.z, ag[t4].z); ag[t4].w = fmaf(wg, s.w, ag[t4].w);
        }
    }
    float bvv = bv[tid], bgv = bg[tid];
    __syncthreads();
    #pragma unroll
    for (int t4 = 0; t4 < 16; ++t4){
        float4 v = av[t4], g = ag[t4];
        v.x += bvv; v.y += bvv; v.z += bvv; v.w += bvv;
        g.x += bgv; g.y += bgv; g.z += bgv; g.w += bgv;
        g.x = 1.f/(1.f+__expf(-g.x)); g.y = 1.f/(1.f+__expf(-g.y));
        g.z = 1.f/(1.f+__expf(-g.z)); g.w = 1.f/(1.f+__expf(-g.w));
        float4 r = make_float4(v.x*g.x, v.y*g.y, v.z*g.z, v.w*g.w);
        *(float4*)&st[tid*64 + t4*4] = r;
    }
    __syncthreads();
    float* hp = h + (size_t)b*DD*LL + t0;
    #pragma unroll
    for (int i = 0; i < 16; ++i){
        int e = tid + i*256;
        int d = e >> 4, t4 = e & 15;
        float4 r = *(const float4*)&st[d*64 + t4*4];
        float* hdst = hp + (size_t)d*LL + t4*4;
        float4 cur = *(const float4*)hdst;
        cur.x += r.x; cur.y += r.y; cur.z += r.z; cur.w += r.w;
        if (MODE == 0) *(float4*)hdst = cur;
        *(float4*)&st[d*64 + t4*4] = cur;
    }
    __syncthreads();
    int t = tid & 63, dg = tid >> 6;
    float s = 0.f, ss = 0.f;
    #pragma unroll
    for (int j = 0; j < 64; ++j){
        float v = st[(dg*64 + j)*64 + t];
        if (MODE == 0){ s += v; ss = fmaf(v, v, ss); }
        else { s = fmaf(gb[dg*64 + j], v, s); }
    }
    red[0][dg][t] = s;
    if (MODE == 0) red[1][dg][t] = ss;
    __syncthreads();
    if (MODE == 0){
        if (tid < 64){
            float S1 = red[0][0][tid] + red[0][1][tid] + red[0][2][tid] + red[0][3][tid];
            float S2 = red[1][0][tid] + red[1][1][tid] + red[1][2][tid] + red[1][3][tid];
            float mu = S1*(1.0f/DD);
            float var = S2*(1.0f/DD) - mu*mu;
            stat[0][tid] = mu;
            stat[1][tid] = rsqrtf(var + 1e-5f);
        }
        __syncthreads();
        float* zp = outp + (size_t)b*DD*LL + t0;
        #pragma unroll
        for (int i = 0; i < 16; ++i){
            int e = tid + i*256;
            int d = e >> 4, t4 = e & 15;
            float4 cur = *(const float4*)&st[d*64 + t4*4];
            float g = gb[d], be = gb[256 + d];
            float4 zv;
            zv.x = (cur.x - stat[0][t4*4+0])*stat[1][t4*4+0]*g + be;
            zv.y = (cur.y - stat[0][t4*4+1])*stat[1][t4*4+1]*g + be;
            zv.z = (cur.z - stat[0][t4*4+2])*stat[1][t4*4+2]*g + be;
            zv.w = (cur.w - stat[0][t4*4+3])*stat[1][t4*4+3]*g + be;
            *(float4*)(zp + (size_t)d*LL + t4*4) = zv;
        }
    } else {
        if (tid < 64){
            float S1 = red[0][0][tid] + red[0][1][tid] + red[0][2][tid] + red[0][3][tid];
            outp[(size_t)b*LL + t0 + tid] = S1 + aux2[0];
        }
    }
}

extern "C" void kernel_launch(void* const* d_in, const int* in_sizes, int n_in,
                              void* d_out, int out_size, void* d_ws, size_t ws_size,
                              hipStream_t stream){
    (void)in_sizes; (void)n_in; (void)out_size; (void)ws_size;
    const float* x      = (const float*)d_in[0];
    const float* lift_w = (const float*)d_in[1];
    const float* lift_b = (const float*)d_in[2];
    const float* theta  = (const float*)d_in[3];
    const float* ln_g   = (const float*)d_in[4];
    const float* ln_b   = (const float*)d_in[5];
    const float* gvw    = (const float*)d_in[6];
    const float* gvb    = (const float*)d_in[7];
    const float* ggw    = (const float*)d_in[8];
    const float* ggb    = (const float*)d_in[9];
    const float* hw     = (const float*)d_in[10];
    const float* hb     = (const float*)d_in[11];
    const float* phr    = (const float*)d_in[12];
    const float* phim   = (const float*)d_in[13];
    float* out = (float*)d_out;

    char* ws = (char*)d_ws;
    size_t off = 0;
    float2* tw  = (float2*)(ws + off); off += (size_t)(LL/2)*sizeof(float2);
    float*  wvt = (float*)(ws + off);  off += (size_t)NDEPTH*DD*DD*4;
    float*  wgt = (float*)(ws + off);  off += (size_t)NDEPTH*DD*DD*4;
    float*  thT = (float*)(ws + off);  off += (size_t)NDEPTH*KK*DD*DD*4;
    off = (off + 255) & ~(size_t)255;
    float*  h   = (float*)(ws + off);  off += (size_t)NB*DD*LL*4;
    float*  z   = (float*)(ws + off);  off += (size_t)NB*DD*LL*4;   // aliased with S
    float*  S   = z;
    unsigned int* XfH = (unsigned int*)(ws + off); off += (size_t)NB*DD*FFP*4;
    off = (off + 255) & ~(size_t)255;
    float2* Sf  = (float2*)(ws + off); off += (size_t)NB*DD*FF*8;

    twiddle_kernel<<<4, 256, 0, stream>>>(tw);
    transpose_glu_kernel<<<(NDEPTH*DD*DD)/256, 256, 0, stream>>>(gvw, ggw, wvt, wgt);
    transpose_theta_kernel<<<dim3(8,8,NDEPTH*KK), 256, 0, stream>>>(theta, thT);
    lift_ln_kernel<<<dim3(LL/64, NB), 256, 0, stream>>>(x, lift_w, lift_b, ln_g, ln_b, h, z);

    for (int layer = 0; layer < NDEPTH; ++layer){
        const float* thL = thT + (size_t)layer*KK*DD*DD;
        fft_fwd_pair_kernel<<<NB*DD/2, 256, 0, stream>>>(z, XfH, tw);
        spectral3_kernel<<<dim3(128,4), 256, 0, stream>>>(XfH, thL, phr, phim, Sf);
        nyq_kernel<<<dim3(16,16), 256, 0, stream>>>(XfH, thL, phr, phim, Sf);
        fft_inv_pair_kernel<<<NB*DD/2, 256, 0, stream>>>(Sf, S, tw);
        if (layer < NDEPTH-1){
            glu_ln_kernel<0><<<dim3(LL/64, NB), 256, 0, stream>>>(
                S, wvt + (size_t)layer*DD*DD, wgt + (size_t)layer*DD*DD,
                gvb + layer*DD, ggb + layer*DD, h, z,
                ln_g + (layer+1)*DD, ln_b + (layer+1)*DD);
        } else {
            glu_ln_kernel<1><<<dim3(LL/64, NB), 256, 0, stream>>>(
                S, wvt + (size_t)layer*DD*DD, wgt + (size_t)layer*DD*DD,
                gvb + layer*DD, ggb + layer*DD, h, out, hw, hb);
        }
    }
}

// Round 5
// 604.563 us; speedup vs baseline: 3.4147x; 1.6849x over previous
//
#include <hip/hip_runtime.h>
#include <math.h>

#define NB 16      // batch
#define CIN 3
#define LL 2048
#define DD 256
#define KK 8
#define NDEPTH 4
#define FF 1025
#define FFP 1032   // padded F stride for half2 Xf
#define LOGL 11

typedef _Float16 half8 __attribute__((ext_vector_type(8)));
typedef float f32x4 __attribute__((ext_vector_type(4)));

union H8 { half8 h8; unsigned int u[4]; uint4 q; };
union H2 { _Float16 h[2]; unsigned int u; };

__device__ inline float2 cmul(const float2 a, const float2 b){
    return make_float2(a.x*b.x - a.y*b.y, a.x*b.y + a.y*b.x);
}

// ---------------- twiddle table ----------------------------------------------------
__global__ void twiddle_kernel(float2* __restrict__ tw){
    int j = blockIdx.x*blockDim.x + threadIdx.x;
    if (j < LL/2){
        double ang = -2.0*3.14159265358979323846*(double)j/(double)LL;
        tw[j] = make_float2((float)cos(ang), (float)sin(ang));
    }
}

// ---------------- convert GLU weights to f16 A-fragment layout ----------------------
// src w[o][d] (per layer, vg: 0=val 1=gate). dest halves:
// ((((layer*2+vg)*16 + (o>>4))*8 + (d>>5))*64 + (o&15) + 16*((d>>3)&3))*8 + (d&7)
__global__ void conv_w_kernel(const float* __restrict__ wv, const float* __restrict__ wg,
                              _Float16* __restrict__ Wf){
    int idx = blockIdx.x*256 + threadIdx.x;   // NDEPTH*2*DD*DD
    int layer = idx >> 17;
    int vg = (idx >> 16) & 1;
    int rem = idx & 65535;
    int o = rem >> 8, d = rem & 255;
    const float* src = (vg ? wg : wv) + ((size_t)layer << 16);
    float val = src[(o << 8) + d];
    size_t dst = ((((size_t)(layer*2+vg)*16 + (o>>4))*8 + (d>>5))*64
                  + (o&15) + 16*((d>>3)&3))*8 + (d&7);
    Wf[dst] = (_Float16)val;
}

// ---------------- transpose theta: [m][h][d] -> [m][d][h], m = layer*KK+l ----------
__global__ void transpose_theta_kernel(const float* __restrict__ in, float* __restrict__ out){
    __shared__ float tile[32][33];
    int m = blockIdx.z;
    int c0 = blockIdx.x*32, r0 = blockIdx.y*32;
    int tx = threadIdx.x & 31, ty = threadIdx.x >> 5;
    const float* src = in + (size_t)m*DD*DD;
    float* dst = out + (size_t)m*DD*DD;
    #pragma unroll
    for (int i = 0; i < 4; ++i){
        tile[ty + i*8][tx] = src[(size_t)(r0 + ty + i*8)*DD + c0 + tx];
    }
    __syncthreads();
    #pragma unroll
    for (int i = 0; i < 4; ++i){
        dst[(size_t)(c0 + ty + i*8)*DD + r0 + tx] = tile[tx][ty + i*8];
    }
}

// ---------------- lift + LayerNorm(layer 0) ----------------------------------------
__global__ __launch_bounds__(256) void lift_ln_kernel(const float* __restrict__ x,
        const float* __restrict__ lw, const float* __restrict__ lb,
        const float* __restrict__ gamma, const float* __restrict__ beta,
        float* __restrict__ h, float* __restrict__ z){
    __shared__ float red[2][4][64];
    __shared__ float stat[2][64];
    __shared__ float gb[512];
    int tid = threadIdx.x;
    int t = tid & 63, dg = tid >> 6;
    int b = blockIdx.y;
    int tg = blockIdx.x*64 + t;
    gb[tid] = gamma[tid];
    gb[256 + tid] = beta[tid];
    const float* xb = x + (size_t)b*CIN*LL;
    float x0 = xb[tg], x1 = xb[LL + tg], x2 = xb[2*LL + tg];
    float coord = (float)tg * (1.0f/(LL-1));
    float hv[64];
    float s = 0.f, ss = 0.f;
    float* hp = h + (size_t)b*DD*LL + tg;
    #pragma unroll
    for (int j = 0; j < 64; ++j){
        int d = dg*64 + j;
        float4 w = *(const float4*)&lw[d*4];
        float v = lb[d];
        v = fmaf(w.x, x0, v); v = fmaf(w.y, x1, v);
        v = fmaf(w.z, x2, v); v = fmaf(w.w, coord, v);
        hv[j] = v;
        s += v; ss = fmaf(v, v, ss);
        hp[(size_t)d*LL] = v;
    }
    red[0][dg][t] = s; red[1][dg][t] = ss;
    __syncthreads();
    if (tid < 64){
        float S1 = red[0][0][tid] + red[0][1][tid] + red[0][2][tid] + red[0][3][tid];
        float S2 = red[1][0][tid] + red[1][1][tid] + red[1][2][tid] + red[1][3][tid];
        float mu = S1*(1.0f/DD);
        float var = S2*(1.0f/DD) - mu*mu;
        stat[0][tid] = mu;
        stat[1][tid] = rsqrtf(var + 1e-5f);
    }
    __syncthreads();
    float mu = stat[0][t], rs = stat[1][t];
    float* zp = z + (size_t)b*DD*LL + tg;
    #pragma unroll
    for (int j = 0; j < 64; ++j){
        int d = dg*64 + j;
        zp[(size_t)d*LL] = (hv[j] - mu)*rs*gb[d] + gb[256 + d];
    }
}

// ---------------- forward FFT, 2 real channels packed; outputs half2 (re,im) -------
__global__ __launch_bounds__(256) void fft_fwd_pair_kernel(const float* __restrict__ in,
                                                           unsigned int* __restrict__ XfH,
                                                           const float2* __restrict__ tw){
    __shared__ float2 a[LL];
    int blk = blockIdx.x;
    const float* src0 = in + (size_t)(blk*2)*LL;
    const float* src1 = src0 + LL;
    int tid = threadIdx.x;
    #pragma unroll
    for (int i = 0; i < LL/256; ++i){
        int idx = tid + i*256;
        int rev = __brev((unsigned)idx) >> (32-LOGL);
        a[rev] = make_float2(src0[idx], src1[idx]);
    }
    __syncthreads();
    for (int s = 0; s < LOGL; ++s){
        int half = 1 << s;
        #pragma unroll
        for (int jj = 0; jj < 4; ++jj){
            int j = tid + jj*256;
            int grp = j >> s;
            int pos = j & (half-1);
            int i1 = (grp << (s+1)) + pos;
            int i2 = i1 + half;
            float2 w = tw[pos << (LOGL-1-s)];
            float2 u = a[i1];
            float2 v = cmul(w, a[i2]);
            a[i1] = make_float2(u.x+v.x, u.y+v.y);
            a[i2] = make_float2(u.x-v.x, u.y-v.y);
        }
        __syncthreads();
    }
    unsigned int* dst0 = XfH + (size_t)(blk*2)*FFP;
    unsigned int* dst1 = dst0 + FFP;
    #pragma unroll
    for (int i = 0; i < 5; ++i){
        int f = tid + i*256;
        if (f <= 1024){
            int m = (LL - f) & (LL-1);
            float2 A = a[f], B = a[m];
            H2 p0, p1;
            p0.h[0] = (_Float16)(0.5f*(A.x + B.x));
            p0.h[1] = (_Float16)(0.5f*(A.y - B.y));
            p1.h[0] = (_Float16)(0.5f*(A.y + B.y));
            p1.h[1] = (_Float16)(0.5f*(B.x - A.x));
            dst0[f] = p0.u;
            dst1[f] = p1.u;
        }
    }
}

// ---------------- inverse FFT: writes S as f16 GLU B-fragments ----------------------
// blk owns channels dl=(blk&127)*2, dl+1 of batch b=blk>>7. For (d,t):
// u32 slot = ((((b*8 + (d>>5))*128 + (t>>4))*64 + (t&15) + 16*((d>>3)&3))*8 + (d&7))/2
__global__ __launch_bounds__(256) void fft_inv_pair_kernel(const float2* __restrict__ in,
                                                           unsigned int* __restrict__ Sfrag,
                                                           const float2* __restrict__ tw){
    __shared__ float2 a[LL];
    int blk = blockIdx.x;
    const float2* src0 = in + (size_t)(blk*2)*FF;
    const float2* src1 = src0 + FF;
    int tid = threadIdx.x;
    #pragma unroll
    for (int i = 0; i < LL/256; ++i){
        int idx = tid + i*256;
        float2 Y;
        if (idx <= 1024){
            float2 s0 = src0[idx], s1 = src1[idx];
            Y = make_float2(s0.x - s1.y, s0.y + s1.x);
        } else {
            int m = LL - idx;
            float2 s0 = src0[m], s1 = src1[m];
            Y = make_float2(s0.x + s1.y, s1.x - s0.y);
        }
        int rev = __brev((unsigned)idx) >> (32-LOGL);
        a[rev] = Y;
    }
    __syncthreads();
    for (int s = 0; s < LOGL; ++s){
        int half = 1 << s;
        #pragma unroll
        for (int jj = 0; jj < 4; ++jj){
            int j = tid + jj*256;
            int grp = j >> s;
            int pos = j & (half-1);
            int i1 = (grp << (s+1)) + pos;
            int i2 = i1 + half;
            float2 w = tw[pos << (LOGL-1-s)];
            w.y = -w.y;
            float2 u = a[i1];
            float2 v = cmul(w, a[i2]);
            a[i1] = make_float2(u.x+v.x, u.y+v.y);
            a[i2] = make_float2(u.x-v.x, u.y-v.y);
        }
        __syncthreads();
    }
    int b = blk >> 7, dl = (blk & 127)*2;
    int kc = dl >> 5, lq4 = (dl >> 3) & 3, jh = (dl & 7) >> 1;
    unsigned int* dst = Sfrag + ((size_t)(b*8 + kc)*128)*64*4;
    const float sc = 1.0f/(float)LL;
    #pragma unroll
    for (int i = 0; i < LL/256; ++i){
        int t = tid + i*256;
        float2 v = a[t];
        H2 p;
        p.h[0] = (_Float16)(v.x*sc);
        p.h[1] = (_Float16)(v.y*sc);
        dst[(((t>>4)*64) + (t&15) + 16*lq4)*4 + jh] = p.u;
    }
}

// ---------------- spectral v3: MFMA ------------------------------------------------
__global__ __launch_bounds__(256, 2) void spectral3_kernel(
    const unsigned int* __restrict__ XfH,   // [b][d][FFP] half2 (re,im)
    const float* __restrict__ thetaT,       // [KK][d][h] this layer
    const float* __restrict__ phr, const float* __restrict__ phim,
    float2* __restrict__ Sf){
    __shared__ unsigned int Apairs[8*64*8];
    __shared__ float2 phi_s[8*KK];
    int tid = threadIdx.x;
    int w = tid >> 6, lane = tid & 63;
    int n = lane & 15, kp = lane >> 4;
    int f0 = blockIdx.x * 8;
    int h0 = blockIdx.y * 64;
    int h = h0 + w*16 + n;

    if (tid < 64){
        int ff = tid >> 3, l = tid & 7;
        phi_s[tid] = make_float2(phr[l*FF + f0 + ff], -phim[l*FF + f0 + ff]);
    }

    f32x4 accre[8], accim[8];
    #pragma unroll
    for (int i = 0; i < 8; ++i){
        accre[i] = (f32x4){0.f,0.f,0.f,0.f};
        accim[i] = (f32x4){0.f,0.f,0.f,0.f};
    }

    for (int kc = 0; kc < 8; ++kc){
        float th[8][8];
        #pragma unroll
        for (int l = 0; l < 8; ++l)
            #pragma unroll
            for (int j = 0; j < 8; ++j)
                th[l][j] = thetaT[((size_t)(l*DD) + kc*32 + kp*8 + j)*DD + h];

        __syncthreads();
        #pragma unroll
        for (int s = 0; s < 2; ++s){
            int b = tid & 15;
            int dd = s*16 + (tid >> 4);
            const uint4* src = (const uint4*)(XfH + ((size_t)(b*DD + kc*32 + dd)*FFP + f0));
            uint4 v0 = src[0], v1 = src[1];
            int L = b + 16*(dd >> 3), j = dd & 7;
            unsigned int vv[8] = {v0.x, v0.y, v0.z, v0.w, v1.x, v1.y, v1.z, v1.w};
            #pragma unroll
            for (int ff = 0; ff < 8; ++ff){
                int A = ff*2048 + L*32 + j*4;
                A ^= ((A >> 7) & 3) << 5;
                *(unsigned int*)((char*)Apairs + A) = vv[ff];
            }
        }
        __syncthreads();

        #pragma unroll
        for (int ff = 0; ff < 8; ++ff){
            float pr[8], pi[8];
            #pragma unroll
            for (int l = 0; l < 8; ++l){
                float2 p = phi_s[ff*8 + l];
                pr[l] = p.x; pi[l] = p.y;
            }
            int Ab = ff*2048 + lane*32;
            Ab ^= ((Ab >> 7) & 3) << 5;
            uint4 lo = *(const uint4*)((const char*)Apairs + Ab);
            uint4 hi = *(const uint4*)((const char*)Apairs + Ab + 16);
            unsigned int dw[8] = {lo.x, lo.y, lo.z, lo.w, hi.x, hi.y, hi.z, hi.w};
            H8 Are, Aim, Anim;
            #pragma unroll
            for (int k = 0; k < 4; ++k){
                Are.u[k]  = __builtin_amdgcn_perm(dw[2*k+1], dw[2*k], 0x05040100u);
                Aim.u[k]  = __builtin_amdgcn_perm(dw[2*k+1], dw[2*k], 0x07060302u);
                Anim.u[k] = Aim.u[k] ^ 0x80008000u;
            }
            float wre[8], wim[8];
            #pragma unroll
            for (int j = 0; j < 8; ++j){
                float re = 0.f, im = 0.f;
                #pragma unroll
                for (int l = 0; l < 8; ++l){
                    re = fmaf(th[l][j], pr[l], re);
                    im = fmaf(th[l][j], pi[l], im);
                }
                wre[j] = re; wim[j] = im;
            }
            H8 Bre, Bim;
            #pragma unroll
            for (int j = 0; j < 8; ++j){
                Bre.h8[j] = (_Float16)wre[j];
                Bim.h8[j] = (_Float16)wim[j];
            }
            accre[ff] = __builtin_amdgcn_mfma_f32_16x16x32_f16(Are.h8,  Bre.h8, accre[ff], 0, 0, 0);
            accre[ff] = __builtin_amdgcn_mfma_f32_16x16x32_f16(Anim.h8, Bim.h8, accre[ff], 0, 0, 0);
            accim[ff] = __builtin_amdgcn_mfma_f32_16x16x32_f16(Are.h8,  Bim.h8, accim[ff], 0, 0, 0);
            accim[ff] = __builtin_amdgcn_mfma_f32_16x16x32_f16(Aim.h8,  Bre.h8, accim[ff], 0, 0, 0);
        }
    }
    #pragma unroll
    for (int ff = 0; ff < 8; ++ff){
        #pragma unroll
        for (int r = 0; r < 4; ++r){
            int b = kp*4 + r;
            Sf[((size_t)(b*DD) + h)*FF + f0 + ff] = make_float2(accre[ff][r], accim[ff][r]);
        }
    }
}

// ---------------- Nyquist bin f=1024 ------------------------------------------------
__global__ __launch_bounds__(256) void nyq_kernel(const unsigned int* __restrict__ XfH,
    const float* __restrict__ thetaT,
    const float* __restrict__ phr, const float* __restrict__ phim,
    float2* __restrict__ Sf){
    __shared__ float2 red[256];
    int tid = threadIdx.x;
    int hb = blockIdx.x, b = blockIdx.y;
    int h = hb*16 + (tid & 15);
    int dp = tid >> 4;
    float pr[KK], pi[KK];
    #pragma unroll
    for (int l = 0; l < KK; ++l){ pr[l] = phr[l*FF + 1024]; pi[l] = -phim[l*FF + 1024]; }
    float2 acc = make_float2(0.f, 0.f);
    for (int j = 0; j < 16; ++j){
        int d = dp*16 + j;
        float wre = 0.f, wim = 0.f;
        #pragma unroll
        for (int l = 0; l < KK; ++l){
            float t = thetaT[((size_t)l*DD + d)*DD + h];
            wre = fmaf(t, pr[l], wre);
            wim = fmaf(t, pi[l], wim);
        }
        H2 u; u.u = XfH[(size_t)(b*DD + d)*FFP + 1024];
        float2 x = make_float2((float)u.h[0], (float)u.h[1]);
        acc.x = fmaf(x.x, wre, fmaf(-x.y, wim, acc.x));
        acc.y = fmaf(x.x, wim, fmaf( x.y, wre, acc.y));
    }
    red[tid] = acc;
    __syncthreads();
    if (tid < 16){
        float2 s = make_float2(0.f, 0.f);
        #pragma unroll
        for (int k = 0; k < 16; ++k){ s.x += red[tid + k*16].x; s.y += red[tid + k*16].y; }
        Sf[((size_t)b*DD + hb*16 + tid)*FF + 1024] = s;
    }
}

// ---------------- GLU via MFMA + residual + fused LN/head ---------------------------
// Block: b = blockIdx.y, 64-t tile at t0 = blockIdx.x*64. 4 waves x 64 o.
// MODE 0: h += GLU, z = LN(h) [aux1=gamma, aux2=beta, outp=z]
// MODE 1: y = head(h + GLU)   [aux1=head_w, aux2=head_b, outp=y]
template<int MODE>
__global__ __launch_bounds__(256, 2) void glu_mfma_kernel(
    const uint4* __restrict__ Sfrag,   // [b][kc][tb][L] 16B-fragments
    const uint4* __restrict__ WfL,     // layer base: [vg][ot][kc][L] 16B
    const float* __restrict__ bv, const float* __restrict__ bg,
    float* __restrict__ h, float* __restrict__ outp,
    const float* __restrict__ aux1, const float* __restrict__ aux2){
    __shared__ float sb[1024];
    __shared__ float red[2][4][4][16];
    __shared__ float stat[2][4][16];
    int tid = threadIdx.x;
    int w = tid >> 6, lane = tid & 63;
    int tl = lane & 15, lq = lane >> 4;
    int b = blockIdx.y, tb4 = blockIdx.x;

    sb[tid] = bv[tid];
    sb[256 + tid] = bg[tid];
    sb[512 + tid] = aux1[tid];
    if (MODE == 0) sb[768 + tid] = aux2[tid];
    __syncthreads();

    f32x4 aV[4][4], aG[4][4];
    #pragma unroll
    for (int mt = 0; mt < 4; ++mt)
        #pragma unroll
        for (int nt = 0; nt < 4; ++nt){
            aV[mt][nt] = (f32x4){0.f,0.f,0.f,0.f};
            aG[mt][nt] = (f32x4){0.f,0.f,0.f,0.f};
        }

    for (int kc = 0; kc < 8; ++kc){
        H8 Bf[4];
        #pragma unroll
        for (int nt = 0; nt < 4; ++nt)
            Bf[nt].q = Sfrag[((size_t)(b*8 + kc)*128 + tb4*4 + nt)*64 + lane];
        H8 Av[4], Ag[4];
        #pragma unroll
        for (int mt = 0; mt < 4; ++mt){
            int ot = w*4 + mt;
            Av[mt].q = WfL[((size_t)(ot)*8 + kc)*64 + lane];
            Ag[mt].q = WfL[((size_t)(16 + ot)*8 + kc)*64 + lane];
        }
        #pragma unroll
        for (int mt = 0; mt < 4; ++mt)
            #pragma unroll
            for (int nt = 0; nt < 4; ++nt){
                aV[mt][nt] = __builtin_amdgcn_mfma_f32_16x16x32_f16(Av[mt].h8, Bf[nt].h8, aV[mt][nt], 0, 0, 0);
                aG[mt][nt] = __builtin_amdgcn_mfma_f32_16x16x32_f16(Ag[mt].h8, Bf[nt].h8, aG[mt][nt], 0, 0, 0);
            }
    }

    // epilogue: cur = h_old + V*sigmoid(G)  (cur stored back into aV)
    #pragma unroll
    for (int mt = 0; mt < 4; ++mt){
        #pragma unroll
        for (int r = 0; r < 4; ++r){
            int o = w*64 + mt*16 + lq*4 + r;
            float bvv = sb[o], bgv = sb[256 + o];
            float* hp = h + ((size_t)(b*DD + o))*LL + tb4*64 + tl;
            #pragma unroll
            for (int nt = 0; nt < 4; ++nt){
                float v = aV[mt][nt][r] + bvv;
                float g = aG[mt][nt][r] + bgv;
                g = 1.0f/(1.0f + __expf(-g));
                float cur = hp[nt*16] + v*g;
                if (MODE == 0) hp[nt*16] = cur;
                aV[mt][nt][r] = cur;
            }
        }
    }

    // reduction over o per t
    float s[4], ss[4];
    #pragma unroll
    for (int nt = 0; nt < 4; ++nt){ s[nt] = 0.f; ss[nt] = 0.f; }
    #pragma unroll
    for (int mt = 0; mt < 4; ++mt)
        #pragma unroll
        for (int r = 0; r < 4; ++r){
            int o = w*64 + mt*16 + lq*4 + r;
            float wo = (MODE == 0) ? 1.0f : sb[512 + o];
            #pragma unroll
            for (int nt = 0; nt < 4; ++nt){
                float cur = aV[mt][nt][r];
                if (MODE == 0){ s[nt] += cur; ss[nt] = fmaf(cur, cur, ss[nt]); }
                else { s[nt] = fmaf(wo, cur, s[nt]); }
            }
        }
    #pragma unroll
    for (int nt = 0; nt < 4; ++nt){
        s[nt] += __shfl_xor(s[nt], 16); s[nt] += __shfl_xor(s[nt], 32);
        if (MODE == 0){ ss[nt] += __shfl_xor(ss[nt], 16); ss[nt] += __shfl_xor(ss[nt], 32); }
    }
    if (lq == 0){
        #pragma unroll
        for (int nt = 0; nt < 4; ++nt){
            red[0][w][nt][tl] = s[nt];
            if (MODE == 0) red[1][w][nt][tl] = ss[nt];
        }
    }
    __syncthreads();
    if (MODE == 0){
        if (tid < 64){
            int nt = tid >> 4, t2 = tid & 15;
            float S1 = red[0][0][nt][t2] + red[0][1][nt][t2] + red[0][2][nt][t2] + red[0][3][nt][t2];
            float S2 = red[1][0][nt][t2] + red[1][1][nt][t2] + red[1][2][nt][t2] + red[1][3][nt][t2];
            float mu = S1*(1.0f/DD);
            float var = S2*(1.0f/DD) - mu*mu;
            stat[0][nt][t2] = mu;
            stat[1][nt][t2] = rsqrtf(var + 1e-5f);
        }
        __syncthreads();
        #pragma unroll
        for (int mt = 0; mt < 4; ++mt){
            #pragma unroll
            for (int r = 0; r < 4; ++r){
                int o = w*64 + mt*16 + lq*4 + r;
                float gam = sb[512 + o], bet = sb[768 + o];
                float* zp = outp + ((size_t)(b*DD + o))*LL + tb4*64 + tl;
                #pragma unroll
                for (int nt = 0; nt < 4; ++nt){
                    float zv = (aV[mt][nt][r] - stat[0][nt][tl])*stat[1][nt][tl]*gam + bet;
                    zp[nt*16] = zv;
                }
            }
        }
    } else {
        if (tid < 64){
            int nt = tid >> 4, t2 = tid & 15;
            float S1 = red[0][0][nt][t2] + red[0][1][nt][t2] + red[0][2][nt][t2] + red[0][3][nt][t2];
            outp[(size_t)b*LL + tb4*64 + tid] = S1 + aux2[0];
        }
    }
}

extern "C" void kernel_launch(void* const* d_in, const int* in_sizes, int n_in,
                              void* d_out, int out_size, void* d_ws, size_t ws_size,
                              hipStream_t stream){
    (void)in_sizes; (void)n_in; (void)out_size; (void)ws_size;
    const float* x      = (const float*)d_in[0];
    const float* lift_w = (const float*)d_in[1];
    const float* lift_b = (const float*)d_in[2];
    const float* theta  = (const float*)d_in[3];
    const float* ln_g   = (const float*)d_in[4];
    const float* ln_b   = (const float*)d_in[5];
    const float* gvw    = (const float*)d_in[6];
    const float* gvb    = (const float*)d_in[7];
    const float* ggw    = (const float*)d_in[8];
    const float* ggb    = (const float*)d_in[9];
    const float* hw     = (const float*)d_in[10];
    const float* hb     = (const float*)d_in[11];
    const float* phr    = (const float*)d_in[12];
    const float* phim   = (const float*)d_in[13];
    float* out = (float*)d_out;

    char* ws = (char*)d_ws;
    size_t off = 0;
    float2* tw  = (float2*)(ws + off); off += (size_t)(LL/2)*sizeof(float2);
    _Float16* Wf = (_Float16*)(ws + off); off += (size_t)NDEPTH*2*DD*DD*2;
    float*  thT = (float*)(ws + off);  off += (size_t)NDEPTH*KK*DD*DD*4;
    off = (off + 255) & ~(size_t)255;
    float*  h   = (float*)(ws + off);  off += (size_t)NB*DD*LL*4;
    float*  z   = (float*)(ws + off);  off += (size_t)NB*DD*LL*4;
    unsigned int* XfH = (unsigned int*)(ws + off); off += (size_t)NB*DD*FFP*4;
    unsigned int* Sfrag = XfH;   // aliased: XfH dead after nyq; Sfrag dead after glu
    off = (off + 255) & ~(size_t)255;
    float2* Sf  = (float2*)(ws + off); off += (size_t)NB*DD*FF*8;

    twiddle_kernel<<<4, 256, 0, stream>>>(tw);
    conv_w_kernel<<<(NDEPTH*2*DD*DD)/256, 256, 0, stream>>>(gvw, ggw, Wf);
    transpose_theta_kernel<<<dim3(8,8,NDEPTH*KK), 256, 0, stream>>>(theta, thT);
    lift_ln_kernel<<<dim3(LL/64, NB), 256, 0, stream>>>(x, lift_w, lift_b, ln_g, ln_b, h, z);

    for (int layer = 0; layer < NDEPTH; ++layer){
        const float* thL = thT + (size_t)layer*KK*DD*DD;
        const uint4* WfL = (const uint4*)(Wf + (size_t)layer*2*DD*DD);
        fft_fwd_pair_kernel<<<NB*DD/2, 256, 0, stream>>>(z, XfH, tw);
        spectral3_kernel<<<dim3(128,4), 256, 0, stream>>>(XfH, thL, phr, phim, Sf);
        nyq_kernel<<<dim3(16,16), 256, 0, stream>>>(XfH, thL, phr, phim, Sf);
        fft_inv_pair_kernel<<<NB*DD/2, 256, 0, stream>>>(Sf, Sfrag, tw);
        if (layer < NDEPTH-1){
            glu_mfma_kernel<0><<<dim3(LL/64, NB), 256, 0, stream>>>(
                (const uint4*)Sfrag, WfL,
                gvb + layer*DD, ggb + layer*DD, h, z,
                ln_g + (layer+1)*DD, ln_b + (layer+1)*DD);
        } else {
            glu_mfma_kernel<1><<<dim3(LL/64, NB), 256, 0, stream>>>(
                (const uint4*)Sfrag, WfL,
                gvb + layer*DD, ggb + layer*DD, h, out, hw, hb);
        }
    }
}